// Round 8
// baseline (736.950 us; speedup 1.0000x reference)
//
#include <hip/hip_runtime.h>
#include <hip/hip_bf16.h>

// Problem: RandomProjectionQuantizer  B=4 N=4096 D=1024 E=512 K=4096
// M = B*N = 16384 rows.
// proj = X @ P (fp32), scores = 2*invr_m*invc_k*(cb_k . proj_m) - cnsq_k,
// nearest = argmax_k score (ties -> min k).
// Round 8: (1) fix_argmax2 batches 4 rows per codeword sweep (4x less L2
// codebook traffic + 4 independent shuffle chains); (2) cb norm+split merged
// into one kernel; (3) gemm1 at 3 blocks/CU.  mfma_argmax untouched (at the
// m97 structural plateau, ~40% of MFMA ceiling).

#define M_ROWS 16384
#define D_DIM  1024
#define E_DIM  512
#define K_CB   4096
#define EPS_N  1e-12f
#define TAU_FIX 1e-4f
#define NEG_INF (-3.4e38f)

typedef short bf16x8 __attribute__((ext_vector_type(8)));
typedef float f32x4  __attribute__((ext_vector_type(4)));

// ---------------------------------------------------------------- helpers
__device__ __forceinline__ unsigned short f32_to_bf16_rtne(float x) {
  unsigned u = __float_as_uint(x);
  unsigned r = u + 0x7FFFu + ((u >> 16) & 1u);
  return (unsigned short)(r >> 16);
}
__device__ __forceinline__ float bf16_bits_to_f32(unsigned short h) {
  return __uint_as_float(((unsigned)h) << 16);
}

// async global->LDS, 16 B per lane; LDS dest = wave-uniform base + lane*16.
__device__ __forceinline__ void g2l16(const void* g, void* l) {
  __builtin_amdgcn_global_load_lds(
      (const __attribute__((address_space(1))) unsigned*)g,
      (__attribute__((address_space(3))) unsigned*)l, 16, 0, 0);
}

// ---------------------------------------------------------------- row norms
__global__ __launch_bounds__(256) void row_norm_kernel(
    const float* __restrict__ src, float* __restrict__ inv_out,
    float* __restrict__ sq_out, int* __restrict__ zero_me) {
  if (zero_me && blockIdx.x == 0 && threadIdx.x == 0) *zero_me = 0;
  int row  = blockIdx.x * 4 + (threadIdx.x >> 6);
  int lane = threadIdx.x & 63;
  const float4* p = (const float4*)(src + (size_t)row * E_DIM);
  float4 v0 = p[lane];
  float4 v1 = p[lane + 64];
  float s = v0.x * v0.x + v0.y * v0.y + v0.z * v0.z + v0.w * v0.w +
            v1.x * v1.x + v1.y * v1.y + v1.z * v1.z + v1.w * v1.w;
#pragma unroll
  for (int m = 32; m; m >>= 1) s += __shfl_xor(s, m, 64);
  float d = fmaxf(sqrtf(s), EPS_N);
  if (sq_out) {
    float q0 = v0.x / d, q1 = v0.y / d, q2 = v0.z / d, q3 = v0.w / d;
    float q4 = v1.x / d, q5 = v1.y / d, q6 = v1.z / d, q7 = v1.w / d;
    float q = q0 * q0 + q1 * q1 + q2 * q2 + q3 * q3 +
              q4 * q4 + q5 * q5 + q6 * q6 + q7 * q7;
#pragma unroll
    for (int m = 32; m; m >>= 1) q += __shfl_xor(q, m, 64);
    if (lane == 0) sq_out[row] = q;
  }
  if (lane == 0) inv_out[row] = 1.0f / d;
}

// ---------------------------------------------------------------- cb norm+split
// One wave per codebook row: computes invc, cnsq AND the bf16 hi/lo split in
// MFMA staging order (lane owns cols lane*8..lane*8+7: kc=lane>>2, q=lane&3).
__global__ __launch_bounds__(256) void cbnorm_split_kernel(
    const float* __restrict__ cb, float* __restrict__ invc,
    float* __restrict__ cnsq, short* __restrict__ hi, short* __restrict__ lo,
    int* __restrict__ zero_me) {
  if (zero_me && blockIdx.x == 0 && threadIdx.x == 0) *zero_me = 0;
  int r    = blockIdx.x * 4 + (threadIdx.x >> 6);
  int lane = threadIdx.x & 63;
  const float* src = cb + (size_t)r * E_DIM + lane * 8;
  float4 v0 = *(const float4*)src;
  float4 v1 = *(const float4*)(src + 4);
  float v[8] = {v0.x, v0.y, v0.z, v0.w, v1.x, v1.y, v1.z, v1.w};
  float s = 0.f;
#pragma unroll
  for (int j = 0; j < 8; ++j) s = fmaf(v[j], v[j], s);
#pragma unroll
  for (int m = 32; m; m >>= 1) s += __shfl_xor(s, m, 64);
  float d = fmaxf(sqrtf(s), EPS_N);
  float q = 0.f;
#pragma unroll
  for (int j = 0; j < 8; ++j) { float t = v[j] / d; q = fmaf(t, t, q); }
#pragma unroll
  for (int m = 32; m; m >>= 1) q += __shfl_xor(q, m, 64);
  if (lane == 0) { cnsq[r] = q; invc[r] = 1.0f / d; }
  // split (raw cb values) into staging order
  union { short s8[8]; float4 f; } H, L;
#pragma unroll
  for (int j = 0; j < 8; ++j) {
    unsigned short h = f32_to_bf16_rtne(v[j]);
    float hf = bf16_bits_to_f32(h);
    H.s8[j] = (short)h;
    L.s8[j] = (short)f32_to_bf16_rtne(v[j] - hf);
  }
  int rb = r >> 7, row = r & 127;
  int kc = lane >> 2, qq = lane & 3;
  size_t idx = (((size_t)(rb * 16 + kc) * 512) + qq * 128 + row) * 8;
  *(float4*)(hi + idx) = H.f;
  *(float4*)(lo + idx) = L.f;
}

// ---------------------------------------------------------------- GEMM1 (fp32)
// C(16384x512) = A(16384x1024) * B(1024x512); epilogue also emits the bf16
// hi/lo split of C directly in MFMA staging order (fuses split_permute).
__global__ __launch_bounds__(256, 3) void gemm1_kernel(
    const float* __restrict__ A, const float* __restrict__ Bm,
    float* __restrict__ C, short* __restrict__ hi, short* __restrict__ lo) {
  __shared__ float As[2][16][132];
  __shared__ float Bs[2][16][128];
  int tid = threadIdx.x;
  int tx = tid & 15, ty = tid >> 4;
  int n0 = blockIdx.x * 128;
  int m0 = blockIdx.y * 128;
  int rb = blockIdx.y;

  int arow = tid >> 2;
  int akq  = (tid & 3) * 4;
  int bk   = tid >> 5;
  int bcol = (tid & 31) * 4;

  const float* Aptr  = A + (size_t)(m0 + arow) * D_DIM + akq;
  const float* Aptr2 = Aptr + (size_t)64 * D_DIM;
  const float* Bptr  = Bm + (size_t)bk * E_DIM + n0 + bcol;
  const float* Bptr2 = Bptr + (size_t)8 * E_DIM;

  float acc[8][8] = {};
  float4 a0 = *(const float4*)(Aptr);
  float4 a1 = *(const float4*)(Aptr2);
  float4 b0 = *(const float4*)(Bptr);
  float4 b1 = *(const float4*)(Bptr2);

  int buf = 0;
  for (int k0 = 0; k0 < D_DIM; k0 += 16) {
    As[buf][akq + 0][arow] = a0.x;
    As[buf][akq + 1][arow] = a0.y;
    As[buf][akq + 2][arow] = a0.z;
    As[buf][akq + 3][arow] = a0.w;
    As[buf][akq + 0][arow + 64] = a1.x;
    As[buf][akq + 1][arow + 64] = a1.y;
    As[buf][akq + 2][arow + 64] = a1.z;
    As[buf][akq + 3][arow + 64] = a1.w;
    *(float4*)&Bs[buf][bk][bcol]     = b0;
    *(float4*)&Bs[buf][bk + 8][bcol] = b1;
    __syncthreads();
    if (k0 + 16 < D_DIM) {
      a0 = *(const float4*)(Aptr + k0 + 16);
      a1 = *(const float4*)(Aptr2 + k0 + 16);
      b0 = *(const float4*)(Bptr + (size_t)(k0 + 16) * E_DIM);
      b1 = *(const float4*)(Bptr2 + (size_t)(k0 + 16) * E_DIM);
    }
#pragma unroll
    for (int kk = 0; kk < 16; ++kk) {
      float4 av0 = *(const float4*)&As[buf][kk][ty * 8];
      float4 av1 = *(const float4*)&As[buf][kk][ty * 8 + 4];
      float4 bv0 = *(const float4*)&Bs[buf][kk][tx * 4];
      float4 bv1 = *(const float4*)&Bs[buf][kk][tx * 4 + 64];
      float a[8] = {av0.x, av0.y, av0.z, av0.w, av1.x, av1.y, av1.z, av1.w};
      float b[8] = {bv0.x, bv0.y, bv0.z, bv0.w, bv1.x, bv1.y, bv1.z, bv1.w};
#pragma unroll
      for (int i = 0; i < 8; ++i)
#pragma unroll
        for (int j = 0; j < 8; ++j) acc[i][j] = fmaf(a[i], b[j], acc[i][j]);
    }
    buf ^= 1;
  }
#pragma unroll
  for (int i = 0; i < 8; ++i) {
    int row = ty * 8 + i;  // 0..127 within the 128-row tile
    float* crow = C + (size_t)(m0 + row) * E_DIM + n0;
    *(float4*)(crow + tx * 4)      = make_float4(acc[i][0], acc[i][1], acc[i][2], acc[i][3]);
    *(float4*)(crow + tx * 4 + 64) = make_float4(acc[i][4], acc[i][5], acc[i][6], acc[i][7]);
    // fused bf16 hi/lo split in MFMA staging order
#pragma unroll
    for (int g = 0; g < 2; ++g) {
      int co = tx * 4 + g * 64;            // col within 128-tile
      int kc = (n0 + co) >> 5;             // global 32-col chunk
      int q  = (co & 31) >> 3;
      int of = co & 7;                     // 0 or 4
      union { short s[4]; float2 f; } H, L;
#pragma unroll
      for (int j = 0; j < 4; ++j) {
        float vv = acc[i][g * 4 + j];
        unsigned short h = f32_to_bf16_rtne(vv);
        float hf = bf16_bits_to_f32(h);
        H.s[j] = (short)h;
        L.s[j] = (short)f32_to_bf16_rtne(vv - hf);
      }
      size_t idx = (((size_t)(rb * 16 + kc) * 512) + q * 128 + row) * 8 + of;
      *(float2*)(hi + idx) = H.f;
      *(float2*)(lo + idx) = L.f;
    }
  }
}

// ---------------------------------------------------------------- MFMA argmax
// grid (64 mblocks, 32 nblocks); block tile 256x128, 4 waves 2x2, wave tile
// 128x64, 16x16x32 bf16 frags, 3 MFMA per fragment pair (hi*hi,hi*lo,lo*hi).
// LDS 48 KB staged by global_load_lds width=16.
__global__ __launch_bounds__(256, 2) void mfma_argmax_kernel(
    const short* __restrict__ Ah, const short* __restrict__ Al,
    const short* __restrict__ Bh, const short* __restrict__ Bl,
    const float* __restrict__ invr, const float* __restrict__ invc,
    const float* __restrict__ cnsq, float* __restrict__ candb,
    float* __restrict__ cands2, int* __restrict__ candi) {
  __shared__ float ldsf[12288];  // 48 KB
  char* lds = (char*)ldsf;
  int tid = threadIdx.x;
  int wid = tid >> 6, lane = tid & 63;
  int mb = blockIdx.x, nb = blockIdx.y;
  int wm = wid >> 1, wn = wid & 1;
  int q = lane >> 4, c0 = lane & 15;
  int rb0 = mb * 2, rb1 = mb * 2 + 1;

  f32x4 zero = {0.f, 0.f, 0.f, 0.f};
  f32x4 acc[8][4];
#pragma unroll
  for (int i = 0; i < 8; ++i)
#pragma unroll
    for (int j = 0; j < 4; ++j) acc[i][j] = zero;

  for (int kc = 0; kc < 16; ++kc) {
    const char* ga[6] = {
        (const char*)Ah + ((size_t)(rb0 * 16 + kc)) * 8192,
        (const char*)Ah + ((size_t)(rb1 * 16 + kc)) * 8192,
        (const char*)Al + ((size_t)(rb0 * 16 + kc)) * 8192,
        (const char*)Al + ((size_t)(rb1 * 16 + kc)) * 8192,
        (const char*)Bh + ((size_t)(nb * 16 + kc)) * 8192,
        (const char*)Bl + ((size_t)(nb * 16 + kc)) * 8192};
#pragma unroll
    for (int p = 0; p < 12; ++p) {
      int s = wid * 12 + p;       // wave-uniform slice 0..47
      int t = s >> 3;             // region 0..5
      int off = (s & 7) * 1024;
      g2l16(ga[t] + off + lane * 16, lds + t * 8192 + off);
    }
    __syncthreads();

    bf16x8 bh[4], bl[4];
#pragma unroll
    for (int ni = 0; ni < 4; ++ni) {
      int boff = (q * 128 + wn * 64 + ni * 16 + c0) << 4;
      bh[ni] = *(const bf16x8*)(lds + 32768 + boff);
      bl[ni] = *(const bf16x8*)(lds + 40960 + boff);
    }
#pragma unroll
    for (int mi = 0; mi < 8; ++mi) {
      int aoff = wm * 8192 + ((q * 128 + mi * 16 + c0) << 4);
      bf16x8 ah = *(const bf16x8*)(lds + aoff);
      bf16x8 al = *(const bf16x8*)(lds + 16384 + aoff);
#pragma unroll
      for (int ni = 0; ni < 4; ++ni) {
        acc[mi][ni] = __builtin_amdgcn_mfma_f32_16x16x32_bf16(
            ah, bh[ni], acc[mi][ni], 0, 0, 0);
        acc[mi][ni] = __builtin_amdgcn_mfma_f32_16x16x32_bf16(
            ah, bl[ni], acc[mi][ni], 0, 0, 0);
        acc[mi][ni] = __builtin_amdgcn_mfma_f32_16x16x32_bf16(
            al, bh[ni], acc[mi][ni], 0, 0, 0);
      }
    }
    __syncthreads();
  }

  // epilogue: per-wave top-2 over its 64 columns, then LDS merge of the two
  // column-half (wn) waves.  Staging LDS is dead now; overlay it.
  float* msb = ldsf;                  // [2][256] best
  float* mss = ldsf + 512;            // [2][256] second
  int*   msi = (int*)(ldsf + 1024);   // [2][256] best idx

  float icv[4], cqv[4];
#pragma unroll
  for (int ni = 0; ni < 4; ++ni) {
    int n = nb * 128 + wn * 64 + ni * 16 + c0;
    icv[ni] = invc[n];
    cqv[ni] = cnsq[n];
  }
#pragma unroll
  for (int mi = 0; mi < 8; ++mi) {
    float4 ir4 = *(const float4*)&invr[mb * 256 + wm * 128 + mi * 16 + q * 4];
    float irv[4] = {ir4.x, ir4.y, ir4.z, ir4.w};
#pragma unroll
    for (int r = 0; r < 4; ++r) {
      float tir = 2.0f * irv[r];
      float b = NEG_INF, s = NEG_INF;
      int bi = 2147483647;
#pragma unroll
      for (int ni = 0; ni < 4; ++ni) {
        float v = acc[mi][ni][r] * tir * icv[ni] - cqv[ni];
        int n = nb * 128 + wn * 64 + ni * 16 + c0;
        if (v > b) { s = b; b = v; bi = n; } else { s = fmaxf(s, v); }
      }
#pragma unroll
      for (int off = 1; off < 16; off <<= 1) {
        float ob = __shfl_xor(b, off, 64);
        float os = __shfl_xor(s, off, 64);
        int   oi = __shfl_xor(bi, off, 64);
        if (ob > b || (ob == b && oi < bi)) {
          s = fmaxf(b, os); b = ob; bi = oi;
        } else {
          s = fmaxf(s, ob);
        }
      }
      if (c0 == 0) {
        int rl = wm * 128 + mi * 16 + q * 4 + r;  // 0..255 within block
        msb[wn * 256 + rl] = b;
        mss[wn * 256 + rl] = s;
        msi[wn * 256 + rl] = bi;
      }
    }
  }
  __syncthreads();
  {
    float b0 = msb[tid],       s0 = mss[tid];
    float b1 = msb[256 + tid], s1 = mss[256 + tid];
    int   i0 = msi[tid],       i1 = msi[256 + tid];
    float B, S; int I;
    if (b1 > b0 || (b1 == b0 && i1 < i0)) {
      B = b1; S = fmaxf(s1, b0); I = i1;
    } else {
      B = b0; S = fmaxf(s0, b1); I = i0;
    }
    size_t o = (size_t)(mb * 256 + tid) * 32 + nb;
    candb[o] = B; cands2[o] = S; candi[o] = I;
  }
}

// ---------------------------------------------------------------- combine
__global__ __launch_bounds__(256) void combine2_kernel(
    const float* __restrict__ candb, const float* __restrict__ cands2,
    const int* __restrict__ candi, int* __restrict__ out,
    int* __restrict__ fixlist, int* __restrict__ fixcount) {
  int r = blockIdx.x * 256 + threadIdx.x;
  float b = NEG_INF, s = NEG_INF;
  int bi = 2147483647;
  const float* pb = candb + (size_t)r * 32;
  const float* ps = cands2 + (size_t)r * 32;
  const int*   pi = candi + (size_t)r * 32;
#pragma unroll 4
  for (int j = 0; j < 32; ++j) {
    float cb_ = pb[j], cs_ = ps[j];
    int ci_ = pi[j];
    if (cb_ > b || (cb_ == b && ci_ < bi)) {
      s = fmaxf(b, cs_); b = cb_; bi = ci_;
    } else {
      s = fmaxf(s, cb_);
    }
  }
  out[r] = bi;
  if (b - s < TAU_FIX) {
    int p = atomicAdd(fixcount, 1);
    if (p < M_ROWS) fixlist[p] = r;
  }
}

// ---------------------------------------------------------------- fixup
// Exact-fp32 rescan of flagged rows, parallel over CODEWORDS, batched 4 rows
// per codeword sweep (4x less L2 codebook traffic, 4 independent reduce
// chains).  grid (16 chunks, 64 row-groups); group = 4 fixlist entries.
__global__ __launch_bounds__(256) void fix_argmax2_kernel(
    const float* __restrict__ P, const float* __restrict__ CB,
    const float* __restrict__ invr, const float* __restrict__ invc,
    const float* __restrict__ cnsq, const int* __restrict__ fixlist,
    const int* __restrict__ fixcount, float* __restrict__ cand_s,
    int* __restrict__ cand_i) {
  int n = *fixcount;
  if (n > M_ROWS) n = M_ROWS;
  int ngroups = (n + 3) >> 2;
  if ((int)blockIdx.y >= ngroups) return;
  __shared__ float wb[4][4];
  __shared__ int   wi[4][4];
  int tid = threadIdx.x, wv = tid >> 6, lane = tid & 63;
  int kbase = blockIdx.x * 256 + wv * 64;

  for (int g = blockIdx.y; g < ngroups; g += 64) {
    int it0 = g * 4;
    int rcount = n - it0; if (rcount > 4) rcount = 4;
    float4 p0[4], p1[4];
    float tir[4];
#pragma unroll
    for (int j = 0; j < 4; ++j) {
      int it = it0 + (j < rcount ? j : 0);
      int r = fixlist[it];
      const float* pr = P + (size_t)r * E_DIM + lane * 8;
      p0[j] = *(const float4*)pr;
      p1[j] = *(const float4*)(pr + 4);
      tir[j] = 2.0f * invr[r];
    }
    float best[4];
    int   bidx[4];
#pragma unroll
    for (int j = 0; j < 4; ++j) { best[j] = NEG_INF; bidx[j] = 2147483647; }
#pragma unroll 2
    for (int i = 0; i < 64; ++i) {
      int k = kbase + i;
      const float* cr = CB + (size_t)k * E_DIM + lane * 8;
      float4 c0 = *(const float4*)cr;
      float4 c1 = *(const float4*)(cr + 4);
      float d[4];
#pragma unroll
      for (int j = 0; j < 4; ++j) {
        float t = 0.f;
        t = fmaf(c0.x, p0[j].x, t); t = fmaf(c0.y, p0[j].y, t);
        t = fmaf(c0.z, p0[j].z, t); t = fmaf(c0.w, p0[j].w, t);
        t = fmaf(c1.x, p1[j].x, t); t = fmaf(c1.y, p1[j].y, t);
        t = fmaf(c1.z, p1[j].z, t); t = fmaf(c1.w, p1[j].w, t);
        d[j] = t;
      }
#pragma unroll
      for (int m = 1; m < 64; m <<= 1) {
#pragma unroll
        for (int j = 0; j < 4; ++j) d[j] += __shfl_xor(d[j], m, 64);
      }
      float ic = invc[k], cq = cnsq[k];
#pragma unroll
      for (int j = 0; j < 4; ++j) {
        float sc = tir[j] * ic * d[j] - cq;
        if (sc > best[j]) { best[j] = sc; bidx[j] = k; }  // ascending k
      }
    }
    if (lane == 0) {
#pragma unroll
      for (int j = 0; j < 4; ++j) { wb[wv][j] = best[j]; wi[wv][j] = bidx[j]; }
    }
    __syncthreads();
    if (tid < 4 && tid < rcount) {
      int j = tid;
      float b = wb[0][j];
      int bi = wi[0][j];
#pragma unroll
      for (int w2 = 1; w2 < 4; ++w2) {
        if (wb[w2][j] > b || (wb[w2][j] == b && wi[w2][j] < bi)) {
          b = wb[w2][j]; bi = wi[w2][j];
        }
      }
      size_t o = (size_t)(it0 + j) * 16 + blockIdx.x;
      cand_s[o] = b; cand_i[o] = bi;
    }
    __syncthreads();
  }
}

__global__ __launch_bounds__(256) void fix_combine2_kernel(
    const float* __restrict__ cand_s, const int* __restrict__ cand_i,
    const int* __restrict__ fixlist, const int* __restrict__ fixcount,
    int* __restrict__ out) {
  int n = *fixcount;
  if (n > M_ROWS) n = M_ROWS;
  int it = blockIdx.x * 256 + threadIdx.x;
  if (it >= n) return;
  float b = NEG_INF;
  int bi = 2147483647;
#pragma unroll 4
  for (int c = 0; c < 16; ++c) {
    float s = cand_s[(size_t)it * 16 + c];
    int ii = cand_i[(size_t)it * 16 + c];
    if (s > b || (s == b && ii < bi)) { b = s; bi = ii; }
  }
  out[fixlist[it]] = bi;
}

// ================================================================ round-1
// fallback path (never taken on this harness; ws_size >= 79 MB observed)
__global__ __launch_bounds__(256, 2) void argmax_kernel(
    const float* __restrict__ P, const float* __restrict__ CB,
    const float* __restrict__ invr, const float* __restrict__ invc,
    const float* __restrict__ cnsq, float* __restrict__ cand_s,
    int* __restrict__ cand_i) {
  __shared__ float As[2][16][68];
  __shared__ float Bs[2][16][256];
  __shared__ float invr_s[64];
  __shared__ float red_s[64][33];
  __shared__ int   red_i[64][33];

  int tid = threadIdx.x;
  int tx = tid & 31, ty = tid >> 5;
  int m0 = blockIdx.x * 64;
  int cbase = blockIdx.y * 2048;
  if (tid < 64) invr_s[tid] = invr[m0 + tid];
  int arow = tid >> 2;
  int akq  = (tid & 3) * 4;
  const float* Aptr = P + (size_t)(m0 + arow) * E_DIM + akq;

  float best[8];
  int   bidx[8];
#pragma unroll
  for (int i = 0; i < 8; ++i) { best[i] = NEG_INF; bidx[i] = 0; }

  for (int n0 = 0; n0 < 2048; n0 += 256) {
    const float* Bptr = CB + (size_t)(cbase + n0 + tid) * E_DIM;
    float4 a0 = *(const float4*)(Aptr);
    float4 b0 = *(const float4*)(Bptr + 0);
    float4 b1 = *(const float4*)(Bptr + 4);
    float4 b2 = *(const float4*)(Bptr + 8);
    float4 b3 = *(const float4*)(Bptr + 12);
    float acc[8][8] = {};
    int buf = 0;
    for (int k0 = 0; k0 < E_DIM; k0 += 16) {
      As[buf][akq + 0][arow] = a0.x;
      As[buf][akq + 1][arow] = a0.y;
      As[buf][akq + 2][arow] = a0.z;
      As[buf][akq + 3][arow] = a0.w;
      Bs[buf][0][tid] = b0.x;  Bs[buf][1][tid] = b0.y;
      Bs[buf][2][tid] = b0.z;  Bs[buf][3][tid] = b0.w;
      Bs[buf][4][tid] = b1.x;  Bs[buf][5][tid] = b1.y;
      Bs[buf][6][tid] = b1.z;  Bs[buf][7][tid] = b1.w;
      Bs[buf][8][tid] = b2.x;  Bs[buf][9][tid] = b2.y;
      Bs[buf][10][tid] = b2.z; Bs[buf][11][tid] = b2.w;
      Bs[buf][12][tid] = b3.x; Bs[buf][13][tid] = b3.y;
      Bs[buf][14][tid] = b3.z; Bs[buf][15][tid] = b3.w;
      __syncthreads();
      if (k0 + 16 < E_DIM) {
        a0 = *(const float4*)(Aptr + k0 + 16);
        b0 = *(const float4*)(Bptr + k0 + 16);
        b1 = *(const float4*)(Bptr + k0 + 20);
        b2 = *(const float4*)(Bptr + k0 + 24);
        b3 = *(const float4*)(Bptr + k0 + 28);
      }
#pragma unroll
      for (int kk = 0; kk < 16; ++kk) {
        float4 av0 = *(const float4*)&As[buf][kk][ty * 8];
        float4 av1 = *(const float4*)&As[buf][kk][ty * 8 + 4];
        float4 bv0 = *(const float4*)&Bs[buf][kk][tx * 4];
        float4 bv1 = *(const float4*)&Bs[buf][kk][tx * 4 + 128];
        float a[8] = {av0.x, av0.y, av0.z, av0.w, av1.x, av1.y, av1.z, av1.w};
        float b[8] = {bv0.x, bv0.y, bv0.z, bv0.w, bv1.x, bv1.y, bv1.z, bv1.w};
#pragma unroll
        for (int i = 0; i < 8; ++i)
#pragma unroll
          for (int j = 0; j < 8; ++j) acc[i][j] = fmaf(a[i], b[j], acc[i][j]);
      }
      buf ^= 1;
    }
#pragma unroll
    for (int j4 = 0; j4 < 2; ++j4) {
      int nbq = cbase + n0 + j4 * 128 + tx * 4;
      float4 ic = *(const float4*)&invc[nbq];
      float4 cq = *(const float4*)&cnsq[nbq];
      float icv[4] = {ic.x, ic.y, ic.z, ic.w};
      float cqv[4] = {cq.x, cq.y, cq.z, cq.w};
#pragma unroll
      for (int i = 0; i < 8; ++i) {
        float ir2 = 2.0f * invr_s[ty * 8 + i];
#pragma unroll
        for (int jj = 0; jj < 4; ++jj) {
          float sc = acc[i][j4 * 4 + jj] * ir2 * icv[jj] - cqv[jj];
          if (sc > best[i]) { best[i] = sc; bidx[i] = nbq + jj; }
        }
      }
    }
  }
  __syncthreads();
#pragma unroll
  for (int i = 0; i < 8; ++i) {
    red_s[ty * 8 + i][tx] = best[i];
    red_i[ty * 8 + i][tx] = bidx[i];
  }
  __syncthreads();
  if (tid < 64) {
    float bs = red_s[tid][0];
    int bi = red_i[tid][0];
#pragma unroll
    for (int t = 1; t < 32; ++t) {
      float s = red_s[tid][t];
      int ii = red_i[tid][t];
      if (s > bs || (s == bs && ii < bi)) { bs = s; bi = ii; }
    }
    cand_s[(size_t)(m0 + tid) * 2 + blockIdx.y] = bs;
    cand_i[(size_t)(m0 + tid) * 2 + blockIdx.y] = bi;
  }
}

__global__ __launch_bounds__(256) void combine_kernel(
    const float* __restrict__ cand_s, const int* __restrict__ cand_i,
    int* __restrict__ out) {
  int r = blockIdx.x * 256 + threadIdx.x;
  float s0 = cand_s[r * 2], s1 = cand_s[r * 2 + 1];
  int i0 = cand_i[r * 2], i1 = cand_i[r * 2 + 1];
  out[r] = (s1 > s0 || (s1 == s0 && i1 < i0)) ? i1 : i0;
}

// ---------------------------------------------------------------- launch
extern "C" void kernel_launch(void* const* d_in, const int* in_sizes, int n_in,
                              void* d_out, int out_size, void* d_ws, size_t ws_size,
                              hipStream_t stream) {
  const float* x  = (const float*)d_in[0];
  const float* rp = (const float*)d_in[1];
  const float* cb = (const float*)d_in[2];
  int* out = (int*)d_out;

  // MFMA-path workspace layout
  char* w = (char*)d_ws;
  float* proj = (float*)w;      w += (size_t)M_ROWS * E_DIM * 4;   // 32 MB
  short* Ah   = (short*)w;      w += (size_t)M_ROWS * E_DIM * 2;   // 16 MB
  short* Al   = (short*)w;      w += (size_t)M_ROWS * E_DIM * 2;   // 16 MB
  short* Bh   = (short*)w;      w += (size_t)K_CB * E_DIM * 2;     // 4 MB
  short* Bl   = (short*)w;      w += (size_t)K_CB * E_DIM * 2;     // 4 MB
  float* invr = (float*)w;      w += M_ROWS * 4;
  float* invc = (float*)w;      w += K_CB * 4;
  float* cnsq = (float*)w;      w += K_CB * 4;
  float* candb  = (float*)w;    w += (size_t)M_ROWS * 32 * 4;      // 2 MB
  float* cands2 = (float*)w;    w += (size_t)M_ROWS * 32 * 4;      // 2 MB
  int*   candi  = (int*)w;      w += (size_t)M_ROWS * 32 * 4;      // 2 MB
  int*   fixlist  = (int*)w;    w += M_ROWS * 4;
  int*   fixcount = (int*)w;    w += 64;
  size_t need = (size_t)(w - (char*)d_ws);
  // gathered-fixup candidate buffers overlay dead Ah region (dead after
  // mfma_argmax; fix_argmax2 runs later) -> no extra workspace needed.
  float* candg_s = (float*)Ah;                            // M_ROWS*16 floats
  int*   candg_i = (int*)((char*)Ah + (size_t)M_ROWS * 16 * 4);

  if (ws_size >= need) {
    cbnorm_split_kernel<<<K_CB / 4, 256, 0, stream>>>(cb, invc, cnsq, Bh, Bl,
                                                      fixcount);
    gemm1_kernel<<<dim3(E_DIM / 128, M_ROWS / 128), 256, 0, stream>>>(
        x, rp, proj, Ah, Al);
    row_norm_kernel<<<M_ROWS / 4, 256, 0, stream>>>(proj, invr, nullptr, nullptr);
    mfma_argmax_kernel<<<dim3(M_ROWS / 256, K_CB / 128), 256, 0, stream>>>(
        Ah, Al, Bh, Bl, invr, invc, cnsq, candb, cands2, candi);
    combine2_kernel<<<M_ROWS / 256, 256, 0, stream>>>(candb, cands2, candi, out,
                                                      fixlist, fixcount);
    fix_argmax2_kernel<<<dim3(16, 64), 256, 0, stream>>>(
        proj, cb, invr, invc, cnsq, fixlist, fixcount, candg_s, candg_i);
    fix_combine2_kernel<<<M_ROWS / 256, 256, 0, stream>>>(candg_s, candg_i,
                                                          fixlist, fixcount, out);
  } else {
    // round-1 fallback (fits in ~35 MB; never taken on this harness)
    float* ws    = (float*)d_ws;
    float* proj1 = ws;
    float* invr1 = proj1 + (size_t)M_ROWS * E_DIM;
    float* invc1 = invr1 + M_ROWS;
    float* cnsq1 = invc1 + K_CB;
    float* cands = cnsq1 + K_CB;
    int*   candi1 = (int*)(cands + (size_t)M_ROWS * 2);

    row_norm_kernel<<<K_CB / 4, 256, 0, stream>>>(cb, invc1, cnsq1, nullptr);
    gemm1_kernel<<<dim3(E_DIM / 128, M_ROWS / 128), 256, 0, stream>>>(
        x, rp, proj1, (short*)cands, (short*)cands);  // dummy targets
    row_norm_kernel<<<M_ROWS / 4, 256, 0, stream>>>(proj1, invr1, nullptr, nullptr);
    argmax_kernel<<<dim3(M_ROWS / 64, 2), 256, 0, stream>>>(proj1, cb, invr1,
                                                            invc1, cnsq1, cands, candi1);
    combine_kernel<<<M_ROWS / 256, 256, 0, stream>>>(cands, candi1, out);
  }
}

// Round 9
// 575.624 us; speedup vs baseline: 1.2803x; 1.2803x over previous
//
#include <hip/hip_runtime.h>
#include <hip/hip_bf16.h>

// Problem: RandomProjectionQuantizer  B=4 N=4096 D=1024 E=512 K=4096
// M = B*N = 16384 rows.
// proj = X @ P (fp32), scores = 2*invr_m*invc_k*(cb_k . proj_m) - cnsq_k,
// nearest = argmax_k score (ties -> min k).
// Round 9: revert gemm1 to __launch_bounds__(256,2) — the (256,3) cap forced
// VGPR=84 < the 64-reg accumulator working set -> scratch spills (750 MB HBM
// traffic, 410+ us).  Keep round-8's merged cbnorm_split + batched fixup.

#define M_ROWS 16384
#define D_DIM  1024
#define E_DIM  512
#define K_CB   4096
#define EPS_N  1e-12f
#define TAU_FIX 1e-4f
#define NEG_INF (-3.4e38f)

typedef short bf16x8 __attribute__((ext_vector_type(8)));
typedef float f32x4  __attribute__((ext_vector_type(4)));

// ---------------------------------------------------------------- helpers
__device__ __forceinline__ unsigned short f32_to_bf16_rtne(float x) {
  unsigned u = __float_as_uint(x);
  unsigned r = u + 0x7FFFu + ((u >> 16) & 1u);
  return (unsigned short)(r >> 16);
}
__device__ __forceinline__ float bf16_bits_to_f32(unsigned short h) {
  return __uint_as_float(((unsigned)h) << 16);
}

// async global->LDS, 16 B per lane; LDS dest = wave-uniform base + lane*16.
__device__ __forceinline__ void g2l16(const void* g, void* l) {
  __builtin_amdgcn_global_load_lds(
      (const __attribute__((address_space(1))) unsigned*)g,
      (__attribute__((address_space(3))) unsigned*)l, 16, 0, 0);
}

// ---------------------------------------------------------------- row norms
__global__ __launch_bounds__(256) void row_norm_kernel(
    const float* __restrict__ src, float* __restrict__ inv_out,
    float* __restrict__ sq_out, int* __restrict__ zero_me) {
  if (zero_me && blockIdx.x == 0 && threadIdx.x == 0) *zero_me = 0;
  int row  = blockIdx.x * 4 + (threadIdx.x >> 6);
  int lane = threadIdx.x & 63;
  const float4* p = (const float4*)(src + (size_t)row * E_DIM);
  float4 v0 = p[lane];
  float4 v1 = p[lane + 64];
  float s = v0.x * v0.x + v0.y * v0.y + v0.z * v0.z + v0.w * v0.w +
            v1.x * v1.x + v1.y * v1.y + v1.z * v1.z + v1.w * v1.w;
#pragma unroll
  for (int m = 32; m; m >>= 1) s += __shfl_xor(s, m, 64);
  float d = fmaxf(sqrtf(s), EPS_N);
  if (sq_out) {
    float q0 = v0.x / d, q1 = v0.y / d, q2 = v0.z / d, q3 = v0.w / d;
    float q4 = v1.x / d, q5 = v1.y / d, q6 = v1.z / d, q7 = v1.w / d;
    float q = q0 * q0 + q1 * q1 + q2 * q2 + q3 * q3 +
              q4 * q4 + q5 * q5 + q6 * q6 + q7 * q7;
#pragma unroll
    for (int m = 32; m; m >>= 1) q += __shfl_xor(q, m, 64);
    if (lane == 0) sq_out[row] = q;
  }
  if (lane == 0) inv_out[row] = 1.0f / d;
}

// ---------------------------------------------------------------- cb norm+split
// One wave per codebook row: computes invc, cnsq AND the bf16 hi/lo split in
// MFMA staging order (lane owns cols lane*8..lane*8+7: kc=lane>>2, q=lane&3).
__global__ __launch_bounds__(256) void cbnorm_split_kernel(
    const float* __restrict__ cb, float* __restrict__ invc,
    float* __restrict__ cnsq, short* __restrict__ hi, short* __restrict__ lo,
    int* __restrict__ zero_me) {
  if (zero_me && blockIdx.x == 0 && threadIdx.x == 0) *zero_me = 0;
  int r    = blockIdx.x * 4 + (threadIdx.x >> 6);
  int lane = threadIdx.x & 63;
  const float* src = cb + (size_t)r * E_DIM + lane * 8;
  float4 v0 = *(const float4*)src;
  float4 v1 = *(const float4*)(src + 4);
  float v[8] = {v0.x, v0.y, v0.z, v0.w, v1.x, v1.y, v1.z, v1.w};
  float s = 0.f;
#pragma unroll
  for (int j = 0; j < 8; ++j) s = fmaf(v[j], v[j], s);
#pragma unroll
  for (int m = 32; m; m >>= 1) s += __shfl_xor(s, m, 64);
  float d = fmaxf(sqrtf(s), EPS_N);
  float q = 0.f;
#pragma unroll
  for (int j = 0; j < 8; ++j) { float t = v[j] / d; q = fmaf(t, t, q); }
#pragma unroll
  for (int m = 32; m; m >>= 1) q += __shfl_xor(q, m, 64);
  if (lane == 0) { cnsq[r] = q; invc[r] = 1.0f / d; }
  // split (raw cb values) into staging order
  union { short s8[8]; float4 f; } H, L;
#pragma unroll
  for (int j = 0; j < 8; ++j) {
    unsigned short h = f32_to_bf16_rtne(v[j]);
    float hf = bf16_bits_to_f32(h);
    H.s8[j] = (short)h;
    L.s8[j] = (short)f32_to_bf16_rtne(v[j] - hf);
  }
  int rb = r >> 7, row = r & 127;
  int kc = lane >> 2, qq = lane & 3;
  size_t idx = (((size_t)(rb * 16 + kc) * 512) + qq * 128 + row) * 8;
  *(float4*)(hi + idx) = H.f;
  *(float4*)(lo + idx) = L.f;
}

// ---------------------------------------------------------------- GEMM1 (fp32)
// C(16384x512) = A(16384x1024) * B(1024x512); epilogue also emits the bf16
// hi/lo split of C directly in MFMA staging order (fuses split_permute).
// __launch_bounds__(256,2): DO NOT raise to 3 — VGPR cap 84 spills the
// 64-register accumulator to scratch (round-8 regression: 750 MB HBM).
__global__ __launch_bounds__(256, 2) void gemm1_kernel(
    const float* __restrict__ A, const float* __restrict__ Bm,
    float* __restrict__ C, short* __restrict__ hi, short* __restrict__ lo) {
  __shared__ float As[2][16][132];
  __shared__ float Bs[2][16][128];
  int tid = threadIdx.x;
  int tx = tid & 15, ty = tid >> 4;
  int n0 = blockIdx.x * 128;
  int m0 = blockIdx.y * 128;
  int rb = blockIdx.y;

  int arow = tid >> 2;
  int akq  = (tid & 3) * 4;
  int bk   = tid >> 5;
  int bcol = (tid & 31) * 4;

  const float* Aptr  = A + (size_t)(m0 + arow) * D_DIM + akq;
  const float* Aptr2 = Aptr + (size_t)64 * D_DIM;
  const float* Bptr  = Bm + (size_t)bk * E_DIM + n0 + bcol;
  const float* Bptr2 = Bptr + (size_t)8 * E_DIM;

  float acc[8][8] = {};
  float4 a0 = *(const float4*)(Aptr);
  float4 a1 = *(const float4*)(Aptr2);
  float4 b0 = *(const float4*)(Bptr);
  float4 b1 = *(const float4*)(Bptr2);

  int buf = 0;
  for (int k0 = 0; k0 < D_DIM; k0 += 16) {
    As[buf][akq + 0][arow] = a0.x;
    As[buf][akq + 1][arow] = a0.y;
    As[buf][akq + 2][arow] = a0.z;
    As[buf][akq + 3][arow] = a0.w;
    As[buf][akq + 0][arow + 64] = a1.x;
    As[buf][akq + 1][arow + 64] = a1.y;
    As[buf][akq + 2][arow + 64] = a1.z;
    As[buf][akq + 3][arow + 64] = a1.w;
    *(float4*)&Bs[buf][bk][bcol]     = b0;
    *(float4*)&Bs[buf][bk + 8][bcol] = b1;
    __syncthreads();
    if (k0 + 16 < D_DIM) {
      a0 = *(const float4*)(Aptr + k0 + 16);
      a1 = *(const float4*)(Aptr2 + k0 + 16);
      b0 = *(const float4*)(Bptr + (size_t)(k0 + 16) * E_DIM);
      b1 = *(const float4*)(Bptr2 + (size_t)(k0 + 16) * E_DIM);
    }
#pragma unroll
    for (int kk = 0; kk < 16; ++kk) {
      float4 av0 = *(const float4*)&As[buf][kk][ty * 8];
      float4 av1 = *(const float4*)&As[buf][kk][ty * 8 + 4];
      float4 bv0 = *(const float4*)&Bs[buf][kk][tx * 4];
      float4 bv1 = *(const float4*)&Bs[buf][kk][tx * 4 + 64];
      float a[8] = {av0.x, av0.y, av0.z, av0.w, av1.x, av1.y, av1.z, av1.w};
      float b[8] = {bv0.x, bv0.y, bv0.z, bv0.w, bv1.x, bv1.y, bv1.z, bv1.w};
#pragma unroll
      for (int i = 0; i < 8; ++i)
#pragma unroll
        for (int j = 0; j < 8; ++j) acc[i][j] = fmaf(a[i], b[j], acc[i][j]);
    }
    buf ^= 1;
  }
#pragma unroll
  for (int i = 0; i < 8; ++i) {
    int row = ty * 8 + i;  // 0..127 within the 128-row tile
    float* crow = C + (size_t)(m0 + row) * E_DIM + n0;
    *(float4*)(crow + tx * 4)      = make_float4(acc[i][0], acc[i][1], acc[i][2], acc[i][3]);
    *(float4*)(crow + tx * 4 + 64) = make_float4(acc[i][4], acc[i][5], acc[i][6], acc[i][7]);
    // fused bf16 hi/lo split in MFMA staging order
#pragma unroll
    for (int g = 0; g < 2; ++g) {
      int co = tx * 4 + g * 64;            // col within 128-tile
      int kc = (n0 + co) >> 5;             // global 32-col chunk
      int q  = (co & 31) >> 3;
      int of = co & 7;                     // 0 or 4
      union { short s[4]; float2 f; } H, L;
#pragma unroll
      for (int j = 0; j < 4; ++j) {
        float vv = acc[i][g * 4 + j];
        unsigned short h = f32_to_bf16_rtne(vv);
        float hf = bf16_bits_to_f32(h);
        H.s[j] = (short)h;
        L.s[j] = (short)f32_to_bf16_rtne(vv - hf);
      }
      size_t idx = (((size_t)(rb * 16 + kc) * 512) + q * 128 + row) * 8 + of;
      *(float2*)(hi + idx) = H.f;
      *(float2*)(lo + idx) = L.f;
    }
  }
}

// ---------------------------------------------------------------- MFMA argmax
// grid (64 mblocks, 32 nblocks); block tile 256x128, 4 waves 2x2, wave tile
// 128x64, 16x16x32 bf16 frags, 3 MFMA per fragment pair (hi*hi,hi*lo,lo*hi).
// LDS 48 KB staged by global_load_lds width=16.
__global__ __launch_bounds__(256, 2) void mfma_argmax_kernel(
    const short* __restrict__ Ah, const short* __restrict__ Al,
    const short* __restrict__ Bh, const short* __restrict__ Bl,
    const float* __restrict__ invr, const float* __restrict__ invc,
    const float* __restrict__ cnsq, float* __restrict__ candb,
    float* __restrict__ cands2, int* __restrict__ candi) {
  __shared__ float ldsf[12288];  // 48 KB
  char* lds = (char*)ldsf;
  int tid = threadIdx.x;
  int wid = tid >> 6, lane = tid & 63;
  int mb = blockIdx.x, nb = blockIdx.y;
  int wm = wid >> 1, wn = wid & 1;
  int q = lane >> 4, c0 = lane & 15;
  int rb0 = mb * 2, rb1 = mb * 2 + 1;

  f32x4 zero = {0.f, 0.f, 0.f, 0.f};
  f32x4 acc[8][4];
#pragma unroll
  for (int i = 0; i < 8; ++i)
#pragma unroll
    for (int j = 0; j < 4; ++j) acc[i][j] = zero;

  for (int kc = 0; kc < 16; ++kc) {
    const char* ga[6] = {
        (const char*)Ah + ((size_t)(rb0 * 16 + kc)) * 8192,
        (const char*)Ah + ((size_t)(rb1 * 16 + kc)) * 8192,
        (const char*)Al + ((size_t)(rb0 * 16 + kc)) * 8192,
        (const char*)Al + ((size_t)(rb1 * 16 + kc)) * 8192,
        (const char*)Bh + ((size_t)(nb * 16 + kc)) * 8192,
        (const char*)Bl + ((size_t)(nb * 16 + kc)) * 8192};
#pragma unroll
    for (int p = 0; p < 12; ++p) {
      int s = wid * 12 + p;       // wave-uniform slice 0..47
      int t = s >> 3;             // region 0..5
      int off = (s & 7) * 1024;
      g2l16(ga[t] + off + lane * 16, lds + t * 8192 + off);
    }
    __syncthreads();

    bf16x8 bh[4], bl[4];
#pragma unroll
    for (int ni = 0; ni < 4; ++ni) {
      int boff = (q * 128 + wn * 64 + ni * 16 + c0) << 4;
      bh[ni] = *(const bf16x8*)(lds + 32768 + boff);
      bl[ni] = *(const bf16x8*)(lds + 40960 + boff);
    }
#pragma unroll
    for (int mi = 0; mi < 8; ++mi) {
      int aoff = wm * 8192 + ((q * 128 + mi * 16 + c0) << 4);
      bf16x8 ah = *(const bf16x8*)(lds + aoff);
      bf16x8 al = *(const bf16x8*)(lds + 16384 + aoff);
#pragma unroll
      for (int ni = 0; ni < 4; ++ni) {
        acc[mi][ni] = __builtin_amdgcn_mfma_f32_16x16x32_bf16(
            ah, bh[ni], acc[mi][ni], 0, 0, 0);
        acc[mi][ni] = __builtin_amdgcn_mfma_f32_16x16x32_bf16(
            ah, bl[ni], acc[mi][ni], 0, 0, 0);
        acc[mi][ni] = __builtin_amdgcn_mfma_f32_16x16x32_bf16(
            al, bh[ni], acc[mi][ni], 0, 0, 0);
      }
    }
    __syncthreads();
  }

  // epilogue: per-wave top-2 over its 64 columns, then LDS merge of the two
  // column-half (wn) waves.  Staging LDS is dead now; overlay it.
  float* msb = ldsf;                  // [2][256] best
  float* mss = ldsf + 512;            // [2][256] second
  int*   msi = (int*)(ldsf + 1024);   // [2][256] best idx

  float icv[4], cqv[4];
#pragma unroll
  for (int ni = 0; ni < 4; ++ni) {
    int n = nb * 128 + wn * 64 + ni * 16 + c0;
    icv[ni] = invc[n];
    cqv[ni] = cnsq[n];
  }
#pragma unroll
  for (int mi = 0; mi < 8; ++mi) {
    float4 ir4 = *(const float4*)&invr[mb * 256 + wm * 128 + mi * 16 + q * 4];
    float irv[4] = {ir4.x, ir4.y, ir4.z, ir4.w};
#pragma unroll
    for (int r = 0; r < 4; ++r) {
      float tir = 2.0f * irv[r];
      float b = NEG_INF, s = NEG_INF;
      int bi = 2147483647;
#pragma unroll
      for (int ni = 0; ni < 4; ++ni) {
        float v = acc[mi][ni][r] * tir * icv[ni] - cqv[ni];
        int n = nb * 128 + wn * 64 + ni * 16 + c0;
        if (v > b) { s = b; b = v; bi = n; } else { s = fmaxf(s, v); }
      }
#pragma unroll
      for (int off = 1; off < 16; off <<= 1) {
        float ob = __shfl_xor(b, off, 64);
        float os = __shfl_xor(s, off, 64);
        int   oi = __shfl_xor(bi, off, 64);
        if (ob > b || (ob == b && oi < bi)) {
          s = fmaxf(b, os); b = ob; bi = oi;
        } else {
          s = fmaxf(s, ob);
        }
      }
      if (c0 == 0) {
        int rl = wm * 128 + mi * 16 + q * 4 + r;  // 0..255 within block
        msb[wn * 256 + rl] = b;
        mss[wn * 256 + rl] = s;
        msi[wn * 256 + rl] = bi;
      }
    }
  }
  __syncthreads();
  {
    float b0 = msb[tid],       s0 = mss[tid];
    float b1 = msb[256 + tid], s1 = mss[256 + tid];
    int   i0 = msi[tid],       i1 = msi[256 + tid];
    float B, S; int I;
    if (b1 > b0 || (b1 == b0 && i1 < i0)) {
      B = b1; S = fmaxf(s1, b0); I = i1;
    } else {
      B = b0; S = fmaxf(s0, b1); I = i0;
    }
    size_t o = (size_t)(mb * 256 + tid) * 32 + nb;
    candb[o] = B; cands2[o] = S; candi[o] = I;
  }
}

// ---------------------------------------------------------------- combine
__global__ __launch_bounds__(256) void combine2_kernel(
    const float* __restrict__ candb, const float* __restrict__ cands2,
    const int* __restrict__ candi, int* __restrict__ out,
    int* __restrict__ fixlist, int* __restrict__ fixcount) {
  int r = blockIdx.x * 256 + threadIdx.x;
  float b = NEG_INF, s = NEG_INF;
  int bi = 2147483647;
  const float* pb = candb + (size_t)r * 32;
  const float* ps = cands2 + (size_t)r * 32;
  const int*   pi = candi + (size_t)r * 32;
#pragma unroll 4
  for (int j = 0; j < 32; ++j) {
    float cb_ = pb[j], cs_ = ps[j];
    int ci_ = pi[j];
    if (cb_ > b || (cb_ == b && ci_ < bi)) {
      s = fmaxf(b, cs_); b = cb_; bi = ci_;
    } else {
      s = fmaxf(s, cb_);
    }
  }
  out[r] = bi;
  if (b - s < TAU_FIX) {
    int p = atomicAdd(fixcount, 1);
    if (p < M_ROWS) fixlist[p] = r;
  }
}

// ---------------------------------------------------------------- fixup
// Exact-fp32 rescan of flagged rows, parallel over CODEWORDS, batched 4 rows
// per codeword sweep.  grid (16 chunks, 64 row-groups).
__global__ __launch_bounds__(256) void fix_argmax2_kernel(
    const float* __restrict__ P, const float* __restrict__ CB,
    const float* __restrict__ invr, const float* __restrict__ invc,
    const float* __restrict__ cnsq, const int* __restrict__ fixlist,
    const int* __restrict__ fixcount, float* __restrict__ cand_s,
    int* __restrict__ cand_i) {
  int n = *fixcount;
  if (n > M_ROWS) n = M_ROWS;
  int ngroups = (n + 3) >> 2;
  if ((int)blockIdx.y >= ngroups) return;
  __shared__ float wb[4][4];
  __shared__ int   wi[4][4];
  int tid = threadIdx.x, wv = tid >> 6, lane = tid & 63;
  int kbase = blockIdx.x * 256 + wv * 64;

  for (int g = blockIdx.y; g < ngroups; g += 64) {
    int it0 = g * 4;
    int rcount = n - it0; if (rcount > 4) rcount = 4;
    float4 p0[4], p1[4];
    float tir[4];
#pragma unroll
    for (int j = 0; j < 4; ++j) {
      int it = it0 + (j < rcount ? j : 0);
      int r = fixlist[it];
      const float* pr = P + (size_t)r * E_DIM + lane * 8;
      p0[j] = *(const float4*)pr;
      p1[j] = *(const float4*)(pr + 4);
      tir[j] = 2.0f * invr[r];
    }
    float best[4];
    int   bidx[4];
#pragma unroll
    for (int j = 0; j < 4; ++j) { best[j] = NEG_INF; bidx[j] = 2147483647; }
#pragma unroll 2
    for (int i = 0; i < 64; ++i) {
      int k = kbase + i;
      const float* cr = CB + (size_t)k * E_DIM + lane * 8;
      float4 c0 = *(const float4*)cr;
      float4 c1 = *(const float4*)(cr + 4);
      float d[4];
#pragma unroll
      for (int j = 0; j < 4; ++j) {
        float t = 0.f;
        t = fmaf(c0.x, p0[j].x, t); t = fmaf(c0.y, p0[j].y, t);
        t = fmaf(c0.z, p0[j].z, t); t = fmaf(c0.w, p0[j].w, t);
        t = fmaf(c1.x, p1[j].x, t); t = fmaf(c1.y, p1[j].y, t);
        t = fmaf(c1.z, p1[j].z, t); t = fmaf(c1.w, p1[j].w, t);
        d[j] = t;
      }
#pragma unroll
      for (int m = 1; m < 64; m <<= 1) {
#pragma unroll
        for (int j = 0; j < 4; ++j) d[j] += __shfl_xor(d[j], m, 64);
      }
      float ic = invc[k], cq = cnsq[k];
#pragma unroll
      for (int j = 0; j < 4; ++j) {
        float sc = tir[j] * ic * d[j] - cq;
        if (sc > best[j]) { best[j] = sc; bidx[j] = k; }  // ascending k
      }
    }
    if (lane == 0) {
#pragma unroll
      for (int j = 0; j < 4; ++j) { wb[wv][j] = best[j]; wi[wv][j] = bidx[j]; }
    }
    __syncthreads();
    if (tid < 4 && tid < rcount) {
      int j = tid;
      float b = wb[0][j];
      int bi = wi[0][j];
#pragma unroll
      for (int w2 = 1; w2 < 4; ++w2) {
        if (wb[w2][j] > b || (wb[w2][j] == b && wi[w2][j] < bi)) {
          b = wb[w2][j]; bi = wi[w2][j];
        }
      }
      size_t o = (size_t)(it0 + j) * 16 + blockIdx.x;
      cand_s[o] = b; cand_i[o] = bi;
    }
    __syncthreads();
  }
}

__global__ __launch_bounds__(256) void fix_combine2_kernel(
    const float* __restrict__ cand_s, const int* __restrict__ cand_i,
    const int* __restrict__ fixlist, const int* __restrict__ fixcount,
    int* __restrict__ out) {
  int n = *fixcount;
  if (n > M_ROWS) n = M_ROWS;
  int it = blockIdx.x * 256 + threadIdx.x;
  if (it >= n) return;
  float b = NEG_INF;
  int bi = 2147483647;
#pragma unroll 4
  for (int c = 0; c < 16; ++c) {
    float s = cand_s[(size_t)it * 16 + c];
    int ii = cand_i[(size_t)it * 16 + c];
    if (s > b || (s == b && ii < bi)) { b = s; bi = ii; }
  }
  out[fixlist[it]] = bi;
}

// ================================================================ round-1
// fallback path (never taken on this harness; ws_size >= 79 MB observed)
__global__ __launch_bounds__(256, 2) void argmax_kernel(
    const float* __restrict__ P, const float* __restrict__ CB,
    const float* __restrict__ invr, const float* __restrict__ invc,
    const float* __restrict__ cnsq, float* __restrict__ cand_s,
    int* __restrict__ cand_i) {
  __shared__ float As[2][16][68];
  __shared__ float Bs[2][16][256];
  __shared__ float invr_s[64];
  __shared__ float red_s[64][33];
  __shared__ int   red_i[64][33];

  int tid = threadIdx.x;
  int tx = tid & 31, ty = tid >> 5;
  int m0 = blockIdx.x * 64;
  int cbase = blockIdx.y * 2048;
  if (tid < 64) invr_s[tid] = invr[m0 + tid];
  int arow = tid >> 2;
  int akq  = (tid & 3) * 4;
  const float* Aptr = P + (size_t)(m0 + arow) * E_DIM + akq;

  float best[8];
  int   bidx[8];
#pragma unroll
  for (int i = 0; i < 8; ++i) { best[i] = NEG_INF; bidx[i] = 0; }

  for (int n0 = 0; n0 < 2048; n0 += 256) {
    const float* Bptr = CB + (size_t)(cbase + n0 + tid) * E_DIM;
    float4 a0 = *(const float4*)(Aptr);
    float4 b0 = *(const float4*)(Bptr + 0);
    float4 b1 = *(const float4*)(Bptr + 4);
    float4 b2 = *(const float4*)(Bptr + 8);
    float4 b3 = *(const float4*)(Bptr + 12);
    float acc[8][8] = {};
    int buf = 0;
    for (int k0 = 0; k0 < E_DIM; k0 += 16) {
      As[buf][akq + 0][arow] = a0.x;
      As[buf][akq + 1][arow] = a0.y;
      As[buf][akq + 2][arow] = a0.z;
      As[buf][akq + 3][arow] = a0.w;
      Bs[buf][0][tid] = b0.x;  Bs[buf][1][tid] = b0.y;
      Bs[buf][2][tid] = b0.z;  Bs[buf][3][tid] = b0.w;
      Bs[buf][4][tid] = b1.x;  Bs[buf][5][tid] = b1.y;
      Bs[buf][6][tid] = b1.z;  Bs[buf][7][tid] = b1.w;
      Bs[buf][8][tid] = b2.x;  Bs[buf][9][tid] = b2.y;
      Bs[buf][10][tid] = b2.z; Bs[buf][11][tid] = b2.w;
      Bs[buf][12][tid] = b3.x; Bs[buf][13][tid] = b3.y;
      Bs[buf][14][tid] = b3.z; Bs[buf][15][tid] = b3.w;
      __syncthreads();
      if (k0 + 16 < E_DIM) {
        a0 = *(const float4*)(Aptr + k0 + 16);
        b0 = *(const float4*)(Bptr + k0 + 16);
        b1 = *(const float4*)(Bptr + k0 + 20);
        b2 = *(const float4*)(Bptr + k0 + 24);
        b3 = *(const float4*)(Bptr + k0 + 28);
      }
#pragma unroll
      for (int kk = 0; kk < 16; ++kk) {
        float4 av0 = *(const float4*)&As[buf][kk][ty * 8];
        float4 av1 = *(const float4*)&As[buf][kk][ty * 8 + 4];
        float4 bv0 = *(const float4*)&Bs[buf][kk][tx * 4];
        float4 bv1 = *(const float4*)&Bs[buf][kk][tx * 4 + 128];
        float a[8] = {av0.x, av0.y, av0.z, av0.w, av1.x, av1.y, av1.z, av1.w};
        float b[8] = {bv0.x, bv0.y, bv0.z, bv0.w, bv1.x, bv1.y, bv1.z, bv1.w};
#pragma unroll
        for (int i = 0; i < 8; ++i)
#pragma unroll
          for (int j = 0; j < 8; ++j) acc[i][j] = fmaf(a[i], b[j], acc[i][j]);
      }
      buf ^= 1;
    }
#pragma unroll
    for (int j4 = 0; j4 < 2; ++j4) {
      int nbq = cbase + n0 + j4 * 128 + tx * 4;
      float4 ic = *(const float4*)&invc[nbq];
      float4 cq = *(const float4*)&cnsq[nbq];
      float icv[4] = {ic.x, ic.y, ic.z, ic.w};
      float cqv[4] = {cq.x, cq.y, cq.z, cq.w};
#pragma unroll
      for (int i = 0; i < 8; ++i) {
        float ir2 = 2.0f * invr_s[ty * 8 + i];
#pragma unroll
        for (int jj = 0; jj < 4; ++jj) {
          float sc = acc[i][j4 * 4 + jj] * ir2 * icv[jj] - cqv[jj];
          if (sc > best[i]) { best[i] = sc; bidx[i] = nbq + jj; }
        }
      }
    }
  }
  __syncthreads();
#pragma unroll
  for (int i = 0; i < 8; ++i) {
    red_s[ty * 8 + i][tx] = best[i];
    red_i[ty * 8 + i][tx] = bidx[i];
  }
  __syncthreads();
  if (tid < 64) {
    float bs = red_s[tid][0];
    int bi = red_i[tid][0];
#pragma unroll
    for (int t = 1; t < 32; ++t) {
      float s = red_s[tid][t];
      int ii = red_i[tid][t];
      if (s > bs || (s == bs && ii < bi)) { bs = s; bi = ii; }
    }
    cand_s[(size_t)(m0 + tid) * 2 + blockIdx.y] = bs;
    cand_i[(size_t)(m0 + tid) * 2 + blockIdx.y] = bi;
  }
}

__global__ __launch_bounds__(256) void combine_kernel(
    const float* __restrict__ cand_s, const int* __restrict__ cand_i,
    int* __restrict__ out) {
  int r = blockIdx.x * 256 + threadIdx.x;
  float s0 = cand_s[r * 2], s1 = cand_s[r * 2 + 1];
  int i0 = cand_i[r * 2], i1 = cand_i[r * 2 + 1];
  out[r] = (s1 > s0 || (s1 == s0 && i1 < i0)) ? i1 : i0;
}

// ---------------------------------------------------------------- launch
extern "C" void kernel_launch(void* const* d_in, const int* in_sizes, int n_in,
                              void* d_out, int out_size, void* d_ws, size_t ws_size,
                              hipStream_t stream) {
  const float* x  = (const float*)d_in[0];
  const float* rp = (const float*)d_in[1];
  const float* cb = (const float*)d_in[2];
  int* out = (int*)d_out;

  // MFMA-path workspace layout
  char* w = (char*)d_ws;
  float* proj = (float*)w;      w += (size_t)M_ROWS * E_DIM * 4;   // 32 MB
  short* Ah   = (short*)w;      w += (size_t)M_ROWS * E_DIM * 2;   // 16 MB
  short* Al   = (short*)w;      w += (size_t)M_ROWS * E_DIM * 2;   // 16 MB
  short* Bh   = (short*)w;      w += (size_t)K_CB * E_DIM * 2;     // 4 MB
  short* Bl   = (short*)w;      w += (size_t)K_CB * E_DIM * 2;     // 4 MB
  float* invr = (float*)w;      w += M_ROWS * 4;
  float* invc = (float*)w;      w += K_CB * 4;
  float* cnsq = (float*)w;      w += K_CB * 4;
  float* candb  = (float*)w;    w += (size_t)M_ROWS * 32 * 4;      // 2 MB
  float* cands2 = (float*)w;    w += (size_t)M_ROWS * 32 * 4;      // 2 MB
  int*   candi  = (int*)w;      w += (size_t)M_ROWS * 32 * 4;      // 2 MB
  int*   fixlist  = (int*)w;    w += M_ROWS * 4;
  int*   fixcount = (int*)w;    w += 64;
  size_t need = (size_t)(w - (char*)d_ws);
  // gathered-fixup candidate buffers overlay dead Ah region (dead after
  // mfma_argmax; fix_argmax2 runs later) -> no extra workspace needed.
  float* candg_s = (float*)Ah;                            // M_ROWS*16 floats
  int*   candg_i = (int*)((char*)Ah + (size_t)M_ROWS * 16 * 4);

  if (ws_size >= need) {
    cbnorm_split_kernel<<<K_CB / 4, 256, 0, stream>>>(cb, invc, cnsq, Bh, Bl,
                                                      fixcount);
    gemm1_kernel<<<dim3(E_DIM / 128, M_ROWS / 128), 256, 0, stream>>>(
        x, rp, proj, Ah, Al);
    row_norm_kernel<<<M_ROWS / 4, 256, 0, stream>>>(proj, invr, nullptr, nullptr);
    mfma_argmax_kernel<<<dim3(M_ROWS / 256, K_CB / 128), 256, 0, stream>>>(
        Ah, Al, Bh, Bl, invr, invc, cnsq, candb, cands2, candi);
    combine2_kernel<<<M_ROWS / 256, 256, 0, stream>>>(candb, cands2, candi, out,
                                                      fixlist, fixcount);
    fix_argmax2_kernel<<<dim3(16, 64), 256, 0, stream>>>(
        proj, cb, invr, invc, cnsq, fixlist, fixcount, candg_s, candg_i);
    fix_combine2_kernel<<<M_ROWS / 256, 256, 0, stream>>>(candg_s, candg_i,
                                                          fixlist, fixcount, out);
  } else {
    // round-1 fallback (fits in ~35 MB; never taken on this harness)
    float* ws    = (float*)d_ws;
    float* proj1 = ws;
    float* invr1 = proj1 + (size_t)M_ROWS * E_DIM;
    float* invc1 = invr1 + M_ROWS;
    float* cnsq1 = invc1 + K_CB;
    float* cands = cnsq1 + K_CB;
    int*   candi1 = (int*)(cands + (size_t)M_ROWS * 2);

    row_norm_kernel<<<K_CB / 4, 256, 0, stream>>>(cb, invc1, cnsq1, nullptr);
    gemm1_kernel<<<dim3(E_DIM / 128, M_ROWS / 128), 256, 0, stream>>>(
        x, rp, proj1, (short*)cands, (short*)cands);  // dummy targets
    row_norm_kernel<<<M_ROWS / 4, 256, 0, stream>>>(proj1, invr1, nullptr, nullptr);
    argmax_kernel<<<dim3(M_ROWS / 64, 2), 256, 0, stream>>>(proj1, cb, invr1,
                                                            invc1, cnsq1, cands, candi1);
    combine_kernel<<<M_ROWS / 256, 256, 0, stream>>>(cands, candi1, out);
  }
}

// Round 10
// 449.224 us; speedup vs baseline: 1.6405x; 1.2814x over previous
//
#include <hip/hip_runtime.h>
#include <hip/hip_bf16.h>

// Problem: RandomProjectionQuantizer  B=4 N=4096 D=1024 E=512 K=4096
// M = B*N = 16384 rows.
// proj = X @ P (fp32), scores = 2*invr_m*invc_k*(cb_k . proj_m) - cnsq_k,
// nearest = argmax_k score (ties -> min k).
// Round 10: gemm1 moved to the matrix pipe via fp16-split MFMA (hi/lo,
// 3 MFMA: hh+hl+lh; dropped lo*lo ~2^-24 = fp32-rounding order).  Inputs
// scaled by 4096 (exact pow2) to avoid fp16-subnormal FTZ on the lo terms;
// acc scaled back by 2^-24.  P pre-split into staged fragment order
// (overlaid on candb/cands2 - no extra workspace); X converted in-kernel.

#define M_ROWS 16384
#define D_DIM  1024
#define E_DIM  512
#define K_CB   4096
#define EPS_N  1e-12f
#define TAU_FIX 1e-4f
#define NEG_INF (-3.4e38f)

typedef short bf16x8 __attribute__((ext_vector_type(8)));
typedef _Float16 f16x8 __attribute__((ext_vector_type(8)));
typedef short s16x4 __attribute__((ext_vector_type(4)));
typedef short s16x8 __attribute__((ext_vector_type(8)));
typedef float f32x4  __attribute__((ext_vector_type(4)));

// ---------------------------------------------------------------- helpers
__device__ __forceinline__ unsigned short f32_to_bf16_rtne(float x) {
  unsigned u = __float_as_uint(x);
  unsigned r = u + 0x7FFFu + ((u >> 16) & 1u);
  return (unsigned short)(r >> 16);
}
__device__ __forceinline__ float bf16_bits_to_f32(unsigned short h) {
  return __uint_as_float(((unsigned)h) << 16);
}
// fp32 -> fp16 hi/lo split (RTNE); returns bit patterns.
__device__ __forceinline__ void split_f16(float x, short& hs, short& ls) {
  _Float16 h = (_Float16)x;
  float hf = (float)h;
  _Float16 l = (_Float16)(x - hf);
  hs = __builtin_bit_cast(short, h);
  ls = __builtin_bit_cast(short, l);
}

// async global->LDS, 16 B per lane; LDS dest = wave-uniform base + lane*16.
__device__ __forceinline__ void g2l16(const void* g, void* l) {
  __builtin_amdgcn_global_load_lds(
      (const __attribute__((address_space(1))) unsigned*)g,
      (__attribute__((address_space(3))) unsigned*)l, 16, 0, 0);
}

// ---------------------------------------------------------------- row norms
__global__ __launch_bounds__(256) void row_norm_kernel(
    const float* __restrict__ src, float* __restrict__ inv_out,
    float* __restrict__ sq_out, int* __restrict__ zero_me) {
  if (zero_me && blockIdx.x == 0 && threadIdx.x == 0) *zero_me = 0;
  int row  = blockIdx.x * 4 + (threadIdx.x >> 6);
  int lane = threadIdx.x & 63;
  const float4* p = (const float4*)(src + (size_t)row * E_DIM);
  float4 v0 = p[lane];
  float4 v1 = p[lane + 64];
  float s = v0.x * v0.x + v0.y * v0.y + v0.z * v0.z + v0.w * v0.w +
            v1.x * v1.x + v1.y * v1.y + v1.z * v1.z + v1.w * v1.w;
#pragma unroll
  for (int m = 32; m; m >>= 1) s += __shfl_xor(s, m, 64);
  float d = fmaxf(sqrtf(s), EPS_N);
  if (sq_out) {
    float q0 = v0.x / d, q1 = v0.y / d, q2 = v0.z / d, q3 = v0.w / d;
    float q4 = v1.x / d, q5 = v1.y / d, q6 = v1.z / d, q7 = v1.w / d;
    float q = q0 * q0 + q1 * q1 + q2 * q2 + q3 * q3 +
              q4 * q4 + q5 * q5 + q6 * q6 + q7 * q7;
#pragma unroll
    for (int m = 32; m; m >>= 1) q += __shfl_xor(q, m, 64);
    if (lane == 0) sq_out[row] = q;
  }
  if (lane == 0) inv_out[row] = 1.0f / d;
}

// ---------------------------------------------------------------- cb norm+split
__global__ __launch_bounds__(256) void cbnorm_split_kernel(
    const float* __restrict__ cb, float* __restrict__ invc,
    float* __restrict__ cnsq, short* __restrict__ hi, short* __restrict__ lo,
    int* __restrict__ zero_me) {
  if (zero_me && blockIdx.x == 0 && threadIdx.x == 0) *zero_me = 0;
  int r    = blockIdx.x * 4 + (threadIdx.x >> 6);
  int lane = threadIdx.x & 63;
  const float* src = cb + (size_t)r * E_DIM + lane * 8;
  float4 v0 = *(const float4*)src;
  float4 v1 = *(const float4*)(src + 4);
  float v[8] = {v0.x, v0.y, v0.z, v0.w, v1.x, v1.y, v1.z, v1.w};
  float s = 0.f;
#pragma unroll
  for (int j = 0; j < 8; ++j) s = fmaf(v[j], v[j], s);
#pragma unroll
  for (int m = 32; m; m >>= 1) s += __shfl_xor(s, m, 64);
  float d = fmaxf(sqrtf(s), EPS_N);
  float q = 0.f;
#pragma unroll
  for (int j = 0; j < 8; ++j) { float t = v[j] / d; q = fmaf(t, t, q); }
#pragma unroll
  for (int m = 32; m; m >>= 1) q += __shfl_xor(q, m, 64);
  if (lane == 0) { cnsq[r] = q; invc[r] = 1.0f / d; }
  union { short s8[8]; float4 f; } H, L;
#pragma unroll
  for (int j = 0; j < 8; ++j) {
    unsigned short h = f32_to_bf16_rtne(v[j]);
    float hf = bf16_bits_to_f32(h);
    H.s8[j] = (short)h;
    L.s8[j] = (short)f32_to_bf16_rtne(v[j] - hf);
  }
  int rb = r >> 7, row = r & 127;
  int kc = lane >> 2, qq = lane & 3;
  size_t idx = (((size_t)(rb * 16 + kc) * 512) + qq * 128 + row) * 8;
  *(float4*)(hi + idx) = H.f;
  *(float4*)(lo + idx) = L.f;
}

// ---------------------------------------------------------------- P split
// P fp32 [1024][512] -> Ph/Pl fp16 (scaled 4096) in MFMA B-staging order:
// dst[(((nb*32+kc)*4 + q)*128 + c)*8 + j] = f16(P[(kc*32+q*8+j)][nb*128+c]*4096)
__global__ __launch_bounds__(256) void psplit_kernel(
    const float* __restrict__ P, short* __restrict__ Ph,
    short* __restrict__ Pl) {
  int tid = threadIdx.x;
#pragma unroll
  for (int i = 0; i < 4; ++i) {
    int g = blockIdx.x * 1024 + i * 256 + tid;  // 0..65535
    int k8 = g >> 9, col = g & 511;
    int nb = col >> 7, c = col & 127;
    int kc = k8 >> 2, q = k8 & 3;
    union { short s8[8]; float4 f; } H, L;
#pragma unroll
    for (int j = 0; j < 8; ++j) {
      float v = P[(size_t)(k8 * 8 + j) * 512 + col] * 4096.0f;
      split_f16(v, H.s8[j], L.s8[j]);
    }
    size_t dst = (((size_t)(nb * 32 + kc) * 4 + q) * 128 + c) * 8;
    *(float4*)(Ph + dst) = H.f;
    *(float4*)(Pl + dst) = L.f;
  }
}

// ---------------------------------------------------------------- GEMM1 (MFMA)
// proj(16384x512) = X(16384x1024) @ P via fp16-split MFMA (hh+hl+lh).
// Block tile 128x128, BK=32, grid (4 nb, 128 mb), 4 waves 2x2, wave 64x64.
// A (X-tile) converted fp32->f16 hi/lo in-kernel; B (P) pre-staged.
// Epilogue: proj fp32 + bf16 hi/lo split in argmax staging order.
__global__ __launch_bounds__(256, 2) void gemm1_mfma_kernel(
    const float* __restrict__ X, const short* __restrict__ Ph,
    const short* __restrict__ Pl, float* __restrict__ proj,
    short* __restrict__ Ah, short* __restrict__ Al) {
  __shared__ short lds_ah[4096];  // [q][row][8]  8 KB
  __shared__ short lds_al[4096];
  __shared__ short lds_bh[4096];  // [q][col][8]
  __shared__ short lds_bl[4096];
  int tid = threadIdx.x;
  int wid = tid >> 6, lane = tid & 63;
  int nb = blockIdx.x, mb = blockIdx.y;
  int m0 = mb * 128, n0 = nb * 128;
  int wm = wid >> 1, wn = wid & 1;
  int q4 = lane >> 4, c0 = lane & 15;

  f32x4 zero = {0.f, 0.f, 0.f, 0.f};
  f32x4 acc[4][4];
#pragma unroll
  for (int i = 0; i < 4; ++i)
#pragma unroll
    for (int j = 0; j < 4; ++j) acc[i][j] = zero;

  for (int kc = 0; kc < 32; ++kc) {
    // stage B via async DMA: 16 x 1KB slices (8 Ph, 8 Pl), 4 per wave.
    const char* gb = (const char*)Ph + ((size_t)(nb * 32 + kc)) * 8192;
    const char* gl = (const char*)Pl + ((size_t)(nb * 32 + kc)) * 8192;
#pragma unroll
    for (int p = 0; p < 4; ++p) {
      int s = wid * 4 + p;          // 0..15, wave-uniform
      int t = s >> 3;               // 0: bh, 1: bl
      int off = (s & 7) * 1024;
      const char* src = (t == 0 ? gb : gl) + off + lane * 16;
      char* dst = (char*)(t == 0 ? lds_bh : lds_bl) + off;
      g2l16(src, dst);
    }
    // stage A: convert fp32 X-tile (128x32) -> f16 hi/lo, scaled 4096.
#pragma unroll
    for (int i = 0; i < 4; ++i) {
      int e = i * 1024 + tid * 4;
      int row = e >> 5, k4 = e & 31;      // k4 in {0,4,...,28}
      int q = k4 >> 3, j0 = k4 & 7;       // j0 in {0,4}
      float4 xv = *(const float4*)(X + (size_t)(m0 + row) * D_DIM + kc * 32 + k4);
      float v[4] = {xv.x * 4096.f, xv.y * 4096.f, xv.z * 4096.f, xv.w * 4096.f};
      s16x4 H, L;
#pragma unroll
      for (int j = 0; j < 4; ++j) {
        short hs, ls;
        split_f16(v[j], hs, ls);
        H[j] = hs; L[j] = ls;
      }
      int o = (q * 128 + row) * 8 + j0;
      *(s16x4*)&lds_ah[o] = H;
      *(s16x4*)&lds_al[o] = L;
    }
    __syncthreads();

    f16x8 bh[4], bl[4];
#pragma unroll
    for (int ni = 0; ni < 4; ++ni) {
      int boff = (q4 * 128 + wn * 64 + ni * 16 + c0) * 8;
      bh[ni] = *(const f16x8*)&lds_bh[boff];
      bl[ni] = *(const f16x8*)&lds_bl[boff];
    }
#pragma unroll
    for (int mi = 0; mi < 4; ++mi) {
      int aoff = (q4 * 128 + wm * 64 + mi * 16 + c0) * 8;
      f16x8 ah = *(const f16x8*)&lds_ah[aoff];
      f16x8 al = *(const f16x8*)&lds_al[aoff];
#pragma unroll
      for (int ni = 0; ni < 4; ++ni) {
        acc[mi][ni] = __builtin_amdgcn_mfma_f32_16x16x32_f16(
            ah, bh[ni], acc[mi][ni], 0, 0, 0);
        acc[mi][ni] = __builtin_amdgcn_mfma_f32_16x16x32_f16(
            ah, bl[ni], acc[mi][ni], 0, 0, 0);
        acc[mi][ni] = __builtin_amdgcn_mfma_f32_16x16x32_f16(
            al, bh[ni], acc[mi][ni], 0, 0, 0);
      }
    }
    __syncthreads();
  }

  // epilogue: scale back 2^-24; write proj fp32 + bf16 hi/lo (argmax layout).
  const float inv_s = 1.0f / 16777216.0f;
#pragma unroll
  for (int ni = 0; ni < 4; ++ni) {
    int gcol = n0 + wn * 64 + ni * 16 + c0;
    int kce = gcol >> 5, qe = (gcol & 31) >> 3, je = gcol & 7;
#pragma unroll
    for (int mi = 0; mi < 4; ++mi) {
#pragma unroll
      for (int r = 0; r < 4; ++r) {
        int rl = wm * 64 + mi * 16 + q4 * 4 + r;  // row within 128-tile
        float val = acc[mi][ni][r] * inv_s;
        proj[(size_t)(m0 + rl) * E_DIM + gcol] = val;
        unsigned short hb = f32_to_bf16_rtne(val);
        size_t idx = (((size_t)(mb * 16 + kce) * 512) + qe * 128 + rl) * 8 + je;
        Ah[idx] = (short)hb;
        Al[idx] = (short)f32_to_bf16_rtne(val - bf16_bits_to_f32(hb));
      }
    }
  }
}

// ---------------------------------------------------------------- MFMA argmax
// grid (64 mblocks, 32 nblocks); block tile 256x128, 4 waves 2x2, wave tile
// 128x64, 16x16x32 bf16 frags, 3 MFMA per fragment pair (hi*hi,hi*lo,lo*hi).
__global__ __launch_bounds__(256, 2) void mfma_argmax_kernel(
    const short* __restrict__ Ah, const short* __restrict__ Al,
    const short* __restrict__ Bh, const short* __restrict__ Bl,
    const float* __restrict__ invr, const float* __restrict__ invc,
    const float* __restrict__ cnsq, float* __restrict__ candb,
    float* __restrict__ cands2, int* __restrict__ candi) {
  __shared__ float ldsf[12288];  // 48 KB
  char* lds = (char*)ldsf;
  int tid = threadIdx.x;
  int wid = tid >> 6, lane = tid & 63;
  int mb = blockIdx.x, nb = blockIdx.y;
  int wm = wid >> 1, wn = wid & 1;
  int q = lane >> 4, c0 = lane & 15;
  int rb0 = mb * 2, rb1 = mb * 2 + 1;

  f32x4 zero = {0.f, 0.f, 0.f, 0.f};
  f32x4 acc[8][4];
#pragma unroll
  for (int i = 0; i < 8; ++i)
#pragma unroll
    for (int j = 0; j < 4; ++j) acc[i][j] = zero;

  for (int kc = 0; kc < 16; ++kc) {
    const char* ga[6] = {
        (const char*)Ah + ((size_t)(rb0 * 16 + kc)) * 8192,
        (const char*)Ah + ((size_t)(rb1 * 16 + kc)) * 8192,
        (const char*)Al + ((size_t)(rb0 * 16 + kc)) * 8192,
        (const char*)Al + ((size_t)(rb1 * 16 + kc)) * 8192,
        (const char*)Bh + ((size_t)(nb * 16 + kc)) * 8192,
        (const char*)Bl + ((size_t)(nb * 16 + kc)) * 8192};
#pragma unroll
    for (int p = 0; p < 12; ++p) {
      int s = wid * 12 + p;       // wave-uniform slice 0..47
      int t = s >> 3;             // region 0..5
      int off = (s & 7) * 1024;
      g2l16(ga[t] + off + lane * 16, lds + t * 8192 + off);
    }
    __syncthreads();

    bf16x8 bh[4], bl[4];
#pragma unroll
    for (int ni = 0; ni < 4; ++ni) {
      int boff = (q * 128 + wn * 64 + ni * 16 + c0) << 4;
      bh[ni] = *(const bf16x8*)(lds + 32768 + boff);
      bl[ni] = *(const bf16x8*)(lds + 40960 + boff);
    }
#pragma unroll
    for (int mi = 0; mi < 8; ++mi) {
      int aoff = wm * 8192 + ((q * 128 + mi * 16 + c0) << 4);
      bf16x8 ah = *(const bf16x8*)(lds + aoff);
      bf16x8 al = *(const bf16x8*)(lds + 16384 + aoff);
#pragma unroll
      for (int ni = 0; ni < 4; ++ni) {
        acc[mi][ni] = __builtin_amdgcn_mfma_f32_16x16x32_bf16(
            ah, bh[ni], acc[mi][ni], 0, 0, 0);
        acc[mi][ni] = __builtin_amdgcn_mfma_f32_16x16x32_bf16(
            ah, bl[ni], acc[mi][ni], 0, 0, 0);
        acc[mi][ni] = __builtin_amdgcn_mfma_f32_16x16x32_bf16(
            al, bh[ni], acc[mi][ni], 0, 0, 0);
      }
    }
    __syncthreads();
  }

  float* msb = ldsf;                  // [2][256] best
  float* mss = ldsf + 512;            // [2][256] second
  int*   msi = (int*)(ldsf + 1024);   // [2][256] best idx

  float icv[4], cqv[4];
#pragma unroll
  for (int ni = 0; ni < 4; ++ni) {
    int n = nb * 128 + wn * 64 + ni * 16 + c0;
    icv[ni] = invc[n];
    cqv[ni] = cnsq[n];
  }
#pragma unroll
  for (int mi = 0; mi < 8; ++mi) {
    float4 ir4 = *(const float4*)&invr[mb * 256 + wm * 128 + mi * 16 + q * 4];
    float irv[4] = {ir4.x, ir4.y, ir4.z, ir4.w};
#pragma unroll
    for (int r = 0; r < 4; ++r) {
      float tir = 2.0f * irv[r];
      float b = NEG_INF, s = NEG_INF;
      int bi = 2147483647;
#pragma unroll
      for (int ni = 0; ni < 4; ++ni) {
        float v = acc[mi][ni][r] * tir * icv[ni] - cqv[ni];
        int n = nb * 128 + wn * 64 + ni * 16 + c0;
        if (v > b) { s = b; b = v; bi = n; } else { s = fmaxf(s, v); }
      }
#pragma unroll
      for (int off = 1; off < 16; off <<= 1) {
        float ob = __shfl_xor(b, off, 64);
        float os = __shfl_xor(s, off, 64);
        int   oi = __shfl_xor(bi, off, 64);
        if (ob > b || (ob == b && oi < bi)) {
          s = fmaxf(b, os); b = ob; bi = oi;
        } else {
          s = fmaxf(s, ob);
        }
      }
      if (c0 == 0) {
        int rl = wm * 128 + mi * 16 + q * 4 + r;  // 0..255 within block
        msb[wn * 256 + rl] = b;
        mss[wn * 256 + rl] = s;
        msi[wn * 256 + rl] = bi;
      }
    }
  }
  __syncthreads();
  {
    float b0 = msb[tid],       s0 = mss[tid];
    float b1 = msb[256 + tid], s1 = mss[256 + tid];
    int   i0 = msi[tid],       i1 = msi[256 + tid];
    float B, S; int I;
    if (b1 > b0 || (b1 == b0 && i1 < i0)) {
      B = b1; S = fmaxf(s1, b0); I = i1;
    } else {
      B = b0; S = fmaxf(s0, b1); I = i0;
    }
    size_t o = (size_t)(mb * 256 + tid) * 32 + nb;
    candb[o] = B; cands2[o] = S; candi[o] = I;
  }
}

// ---------------------------------------------------------------- combine
__global__ __launch_bounds__(256) void combine2_kernel(
    const float* __restrict__ candb, const float* __restrict__ cands2,
    const int* __restrict__ candi, int* __restrict__ out,
    int* __restrict__ fixlist, int* __restrict__ fixcount) {
  int r = blockIdx.x * 256 + threadIdx.x;
  float b = NEG_INF, s = NEG_INF;
  int bi = 2147483647;
  const float* pb = candb + (size_t)r * 32;
  const float* ps = cands2 + (size_t)r * 32;
  const int*   pi = candi + (size_t)r * 32;
#pragma unroll 4
  for (int j = 0; j < 32; ++j) {
    float cb_ = pb[j], cs_ = ps[j];
    int ci_ = pi[j];
    if (cb_ > b || (cb_ == b && ci_ < bi)) {
      s = fmaxf(b, cs_); b = cb_; bi = ci_;
    } else {
      s = fmaxf(s, cb_);
    }
  }
  out[r] = bi;
  if (b - s < TAU_FIX) {
    int p = atomicAdd(fixcount, 1);
    if (p < M_ROWS) fixlist[p] = r;
  }
}

// ---------------------------------------------------------------- fixup
__global__ __launch_bounds__(256) void fix_argmax2_kernel(
    const float* __restrict__ P, const float* __restrict__ CB,
    const float* __restrict__ invr, const float* __restrict__ invc,
    const float* __restrict__ cnsq, const int* __restrict__ fixlist,
    const int* __restrict__ fixcount, float* __restrict__ cand_s,
    int* __restrict__ cand_i) {
  int n = *fixcount;
  if (n > M_ROWS) n = M_ROWS;
  int ngroups = (n + 3) >> 2;
  if ((int)blockIdx.y >= ngroups) return;
  __shared__ float wb[4][4];
  __shared__ int   wi[4][4];
  int tid = threadIdx.x, wv = tid >> 6, lane = tid & 63;
  int kbase = blockIdx.x * 256 + wv * 64;

  for (int g = blockIdx.y; g < ngroups; g += 64) {
    int it0 = g * 4;
    int rcount = n - it0; if (rcount > 4) rcount = 4;
    float4 p0[4], p1[4];
    float tir[4];
#pragma unroll
    for (int j = 0; j < 4; ++j) {
      int it = it0 + (j < rcount ? j : 0);
      int r = fixlist[it];
      const float* pr = P + (size_t)r * E_DIM + lane * 8;
      p0[j] = *(const float4*)pr;
      p1[j] = *(const float4*)(pr + 4);
      tir[j] = 2.0f * invr[r];
    }
    float best[4];
    int   bidx[4];
#pragma unroll
    for (int j = 0; j < 4; ++j) { best[j] = NEG_INF; bidx[j] = 2147483647; }
#pragma unroll 2
    for (int i = 0; i < 64; ++i) {
      int k = kbase + i;
      const float* cr = CB + (size_t)k * E_DIM + lane * 8;
      float4 c0 = *(const float4*)cr;
      float4 c1 = *(const float4*)(cr + 4);
      float d[4];
#pragma unroll
      for (int j = 0; j < 4; ++j) {
        float t = 0.f;
        t = fmaf(c0.x, p0[j].x, t); t = fmaf(c0.y, p0[j].y, t);
        t = fmaf(c0.z, p0[j].z, t); t = fmaf(c0.w, p0[j].w, t);
        t = fmaf(c1.x, p1[j].x, t); t = fmaf(c1.y, p1[j].y, t);
        t = fmaf(c1.z, p1[j].z, t); t = fmaf(c1.w, p1[j].w, t);
        d[j] = t;
      }
#pragma unroll
      for (int m = 1; m < 64; m <<= 1) {
#pragma unroll
        for (int j = 0; j < 4; ++j) d[j] += __shfl_xor(d[j], m, 64);
      }
      float ic = invc[k], cq = cnsq[k];
#pragma unroll
      for (int j = 0; j < 4; ++j) {
        float sc = tir[j] * ic * d[j] - cq;
        if (sc > best[j]) { best[j] = sc; bidx[j] = k; }  // ascending k
      }
    }
    if (lane == 0) {
#pragma unroll
      for (int j = 0; j < 4; ++j) { wb[wv][j] = best[j]; wi[wv][j] = bidx[j]; }
    }
    __syncthreads();
    if (tid < 4 && tid < rcount) {
      int j = tid;
      float b = wb[0][j];
      int bi = wi[0][j];
#pragma unroll
      for (int w2 = 1; w2 < 4; ++w2) {
        if (wb[w2][j] > b || (wb[w2][j] == b && wi[w2][j] < bi)) {
          b = wb[w2][j]; bi = wi[w2][j];
        }
      }
      size_t o = (size_t)(it0 + j) * 16 + blockIdx.x;
      cand_s[o] = b; cand_i[o] = bi;
    }
    __syncthreads();
  }
}

__global__ __launch_bounds__(256) void fix_combine2_kernel(
    const float* __restrict__ cand_s, const int* __restrict__ cand_i,
    const int* __restrict__ fixlist, const int* __restrict__ fixcount,
    int* __restrict__ out) {
  int n = *fixcount;
  if (n > M_ROWS) n = M_ROWS;
  int it = blockIdx.x * 256 + threadIdx.x;
  if (it >= n) return;
  float b = NEG_INF;
  int bi = 2147483647;
#pragma unroll 4
  for (int c = 0; c < 16; ++c) {
    float s = cand_s[(size_t)it * 16 + c];
    int ii = cand_i[(size_t)it * 16 + c];
    if (s > b || (s == b && ii < bi)) { b = s; bi = ii; }
  }
  out[fixlist[it]] = bi;
}

// ================================================================ fallback
// round-1 exact path (only if ws too small; fp32 gemm1 kept for it)
__global__ __launch_bounds__(256, 2) void gemm1_kernel(
    const float* __restrict__ A, const float* __restrict__ Bm,
    float* __restrict__ C) {
  __shared__ float As[2][16][132];
  __shared__ float Bs[2][16][128];
  int tid = threadIdx.x;
  int tx = tid & 15, ty = tid >> 4;
  int n0 = blockIdx.x * 128;
  int m0 = blockIdx.y * 128;

  int arow = tid >> 2;
  int akq  = (tid & 3) * 4;
  int bk   = tid >> 5;
  int bcol = (tid & 31) * 4;

  const float* Aptr  = A + (size_t)(m0 + arow) * D_DIM + akq;
  const float* Aptr2 = Aptr + (size_t)64 * D_DIM;
  const float* Bptr  = Bm + (size_t)bk * E_DIM + n0 + bcol;
  const float* Bptr2 = Bptr + (size_t)8 * E_DIM;

  float acc[8][8] = {};
  float4 a0 = *(const float4*)(Aptr);
  float4 a1 = *(const float4*)(Aptr2);
  float4 b0 = *(const float4*)(Bptr);
  float4 b1 = *(const float4*)(Bptr2);

  int buf = 0;
  for (int k0 = 0; k0 < D_DIM; k0 += 16) {
    As[buf][akq + 0][arow] = a0.x;
    As[buf][akq + 1][arow] = a0.y;
    As[buf][akq + 2][arow] = a0.z;
    As[buf][akq + 3][arow] = a0.w;
    As[buf][akq + 0][arow + 64] = a1.x;
    As[buf][akq + 1][arow + 64] = a1.y;
    As[buf][akq + 2][arow + 64] = a1.z;
    As[buf][akq + 3][arow + 64] = a1.w;
    *(float4*)&Bs[buf][bk][bcol]     = b0;
    *(float4*)&Bs[buf][bk + 8][bcol] = b1;
    __syncthreads();
    if (k0 + 16 < D_DIM) {
      a0 = *(const float4*)(Aptr + k0 + 16);
      a1 = *(const float4*)(Aptr2 + k0 + 16);
      b0 = *(const float4*)(Bptr + (size_t)(k0 + 16) * E_DIM);
      b1 = *(const float4*)(Bptr2 + (size_t)(k0 + 16) * E_DIM);
    }
#pragma unroll
    for (int kk = 0; kk < 16; ++kk) {
      float4 av0 = *(const float4*)&As[buf][kk][ty * 8];
      float4 av1 = *(const float4*)&As[buf][kk][ty * 8 + 4];
      float4 bv0 = *(const float4*)&Bs[buf][kk][tx * 4];
      float4 bv1 = *(const float4*)&Bs[buf][kk][tx * 4 + 64];
      float a[8] = {av0.x, av0.y, av0.z, av0.w, av1.x, av1.y, av1.z, av1.w};
      float b[8] = {bv0.x, bv0.y, bv0.z, bv0.w, bv1.x, bv1.y, bv1.z, bv1.w};
#pragma unroll
      for (int i = 0; i < 8; ++i)
#pragma unroll
        for (int j = 0; j < 8; ++j) acc[i][j] = fmaf(a[i], b[j], acc[i][j]);
    }
    buf ^= 1;
  }
#pragma unroll
  for (int i = 0; i < 8; ++i) {
    float* crow = C + (size_t)(m0 + ty * 8 + i) * E_DIM + n0;
    *(float4*)(crow + tx * 4)      = make_float4(acc[i][0], acc[i][1], acc[i][2], acc[i][3]);
    *(float4*)(crow + tx * 4 + 64) = make_float4(acc[i][4], acc[i][5], acc[i][6], acc[i][7]);
  }
}

__global__ __launch_bounds__(256, 2) void argmax_kernel(
    const float* __restrict__ P, const float* __restrict__ CB,
    const float* __restrict__ invr, const float* __restrict__ invc,
    const float* __restrict__ cnsq, float* __restrict__ cand_s,
    int* __restrict__ cand_i) {
  __shared__ float As[2][16][68];
  __shared__ float Bs[2][16][256];
  __shared__ float invr_s[64];
  __shared__ float red_s[64][33];
  __shared__ int   red_i[64][33];

  int tid = threadIdx.x;
  int tx = tid & 31, ty = tid >> 5;
  int m0 = blockIdx.x * 64;
  int cbase = blockIdx.y * 2048;
  if (tid < 64) invr_s[tid] = invr[m0 + tid];
  int arow = tid >> 2;
  int akq  = (tid & 3) * 4;
  const float* Aptr = P + (size_t)(m0 + arow) * E_DIM + akq;

  float best[8];
  int   bidx[8];
#pragma unroll
  for (int i = 0; i < 8; ++i) { best[i] = NEG_INF; bidx[i] = 0; }

  for (int n0 = 0; n0 < 2048; n0 += 256) {
    const float* Bptr = CB + (size_t)(cbase + n0 + tid) * E_DIM;
    float4 a0 = *(const float4*)(Aptr);
    float4 b0 = *(const float4*)(Bptr + 0);
    float4 b1 = *(const float4*)(Bptr + 4);
    float4 b2 = *(const float4*)(Bptr + 8);
    float4 b3 = *(const float4*)(Bptr + 12);
    float acc[8][8] = {};
    int buf = 0;
    for (int k0 = 0; k0 < E_DIM; k0 += 16) {
      As[buf][akq + 0][arow] = a0.x;
      As[buf][akq + 1][arow] = a0.y;
      As[buf][akq + 2][arow] = a0.z;
      As[buf][akq + 3][arow] = a0.w;
      Bs[buf][0][tid] = b0.x;  Bs[buf][1][tid] = b0.y;
      Bs[buf][2][tid] = b0.z;  Bs[buf][3][tid] = b0.w;
      Bs[buf][4][tid] = b1.x;  Bs[buf][5][tid] = b1.y;
      Bs[buf][6][tid] = b1.z;  Bs[buf][7][tid] = b1.w;
      Bs[buf][8][tid] = b2.x;  Bs[buf][9][tid] = b2.y;
      Bs[buf][10][tid] = b2.z; Bs[buf][11][tid] = b2.w;
      Bs[buf][12][tid] = b3.x; Bs[buf][13][tid] = b3.y;
      Bs[buf][14][tid] = b3.z; Bs[buf][15][tid] = b3.w;
      __syncthreads();
      if (k0 + 16 < E_DIM) {
        a0 = *(const float4*)(Aptr + k0 + 16);
        b0 = *(const float4*)(Bptr + k0 + 16);
        b1 = *(const float4*)(Bptr + k0 + 20);
        b2 = *(const float4*)(Bptr + k0 + 24);
        b3 = *(const float4*)(Bptr + k0 + 28);
      }
#pragma unroll
      for (int kk = 0; kk < 16; ++kk) {
        float4 av0 = *(const float4*)&As[buf][kk][ty * 8];
        float4 av1 = *(const float4*)&As[buf][kk][ty * 8 + 4];
        float4 bv0 = *(const float4*)&Bs[buf][kk][tx * 4];
        float4 bv1 = *(const float4*)&Bs[buf][kk][tx * 4 + 128];
        float a[8] = {av0.x, av0.y, av0.z, av0.w, av1.x, av1.y, av1.z, av1.w};
        float b[8] = {bv0.x, bv0.y, bv0.z, bv0.w, bv1.x, bv1.y, bv1.z, bv1.w};
#pragma unroll
        for (int i = 0; i < 8; ++i)
#pragma unroll
          for (int j = 0; j < 8; ++j) acc[i][j] = fmaf(a[i], b[j], acc[i][j]);
      }
      buf ^= 1;
    }
#pragma unroll
    for (int j4 = 0; j4 < 2; ++j4) {
      int nbq = cbase + n0 + j4 * 128 + tx * 4;
      float4 ic = *(const float4*)&invc[nbq];
      float4 cq = *(const float4*)&cnsq[nbq];
      float icv[4] = {ic.x, ic.y, ic.z, ic.w};
      float cqv[4] = {cq.x, cq.y, cq.z, cq.w};
#pragma unroll
      for (int i = 0; i < 8; ++i) {
        float ir2 = 2.0f * invr_s[ty * 8 + i];
#pragma unroll
        for (int jj = 0; jj < 4; ++jj) {
          float sc = acc[i][j4 * 4 + jj] * ir2 * icv[jj] - cqv[jj];
          if (sc > best[i]) { best[i] = sc; bidx[i] = nbq + jj; }
        }
      }
    }
  }
  __syncthreads();
#pragma unroll
  for (int i = 0; i < 8; ++i) {
    red_s[ty * 8 + i][tx] = best[i];
    red_i[ty * 8 + i][tx] = bidx[i];
  }
  __syncthreads();
  if (tid < 64) {
    float bs = red_s[tid][0];
    int bi = red_i[tid][0];
#pragma unroll
    for (int t = 1; t < 32; ++t) {
      float s = red_s[tid][t];
      int ii = red_i[tid][t];
      if (s > bs || (s == bs && ii < bi)) { bs = s; bi = ii; }
    }
    cand_s[(size_t)(m0 + tid) * 2 + blockIdx.y] = bs;
    cand_i[(size_t)(m0 + tid) * 2 + blockIdx.y] = bi;
  }
}

__global__ __launch_bounds__(256) void combine_kernel(
    const float* __restrict__ cand_s, const int* __restrict__ cand_i,
    int* __restrict__ out) {
  int r = blockIdx.x * 256 + threadIdx.x;
  float s0 = cand_s[r * 2], s1 = cand_s[r * 2 + 1];
  int i0 = cand_i[r * 2], i1 = cand_i[r * 2 + 1];
  out[r] = (s1 > s0 || (s1 == s0 && i1 < i0)) ? i1 : i0;
}

// ---------------------------------------------------------------- launch
extern "C" void kernel_launch(void* const* d_in, const int* in_sizes, int n_in,
                              void* d_out, int out_size, void* d_ws, size_t ws_size,
                              hipStream_t stream) {
  const float* x  = (const float*)d_in[0];
  const float* rp = (const float*)d_in[1];
  const float* cb = (const float*)d_in[2];
  int* out = (int*)d_out;

  // MFMA-path workspace layout
  char* w = (char*)d_ws;
  float* proj = (float*)w;      w += (size_t)M_ROWS * E_DIM * 4;   // 32 MB
  short* Ah   = (short*)w;      w += (size_t)M_ROWS * E_DIM * 2;   // 16 MB
  short* Al   = (short*)w;      w += (size_t)M_ROWS * E_DIM * 2;   // 16 MB
  short* Bh   = (short*)w;      w += (size_t)K_CB * E_DIM * 2;     // 4 MB
  short* Bl   = (short*)w;      w += (size_t)K_CB * E_DIM * 2;     // 4 MB
  float* invr = (float*)w;      w += M_ROWS * 4;
  float* invc = (float*)w;      w += K_CB * 4;
  float* cnsq = (float*)w;      w += K_CB * 4;
  float* candb  = (float*)w;    w += (size_t)M_ROWS * 32 * 4;      // 2 MB
  float* cands2 = (float*)w;    w += (size_t)M_ROWS * 32 * 4;      // 2 MB
  int*   candi  = (int*)w;      w += (size_t)M_ROWS * 32 * 4;      // 2 MB
  int*   fixlist  = (int*)w;    w += M_ROWS * 4;
  int*   fixcount = (int*)w;    w += 64;
  size_t need = (size_t)(w - (char*)d_ws);
  // overlays (lifetimes disjoint):
  //  Ph/Pl (psplit -> gemm1_mfma) live in candb/cands2 (first written by
  //  mfma_argmax, which runs after gemm1).  candg (fixup) lives in dead Ah.
  short* Ph = (short*)candb;    // 512*1024 shorts = 1 MB  (< 2 MB region)
  short* Pl = (short*)cands2;
  float* candg_s = (float*)Ah;
  int*   candg_i = (int*)((char*)Ah + (size_t)M_ROWS * 16 * 4);

  if (ws_size >= need) {
    cbnorm_split_kernel<<<K_CB / 4, 256, 0, stream>>>(cb, invc, cnsq, Bh, Bl,
                                                      fixcount);
    psplit_kernel<<<64, 256, 0, stream>>>(rp, Ph, Pl);
    gemm1_mfma_kernel<<<dim3(E_DIM / 128, M_ROWS / 128), 256, 0, stream>>>(
        x, Ph, Pl, proj, Ah, Al);
    row_norm_kernel<<<M_ROWS / 4, 256, 0, stream>>>(proj, invr, nullptr, nullptr);
    mfma_argmax_kernel<<<dim3(M_ROWS / 256, K_CB / 128), 256, 0, stream>>>(
        Ah, Al, Bh, Bl, invr, invc, cnsq, candb, cands2, candi);
    combine2_kernel<<<M_ROWS / 256, 256, 0, stream>>>(candb, cands2, candi, out,
                                                      fixlist, fixcount);
    fix_argmax2_kernel<<<dim3(16, 64), 256, 0, stream>>>(
        proj, cb, invr, invc, cnsq, fixlist, fixcount, candg_s, candg_i);
    fix_combine2_kernel<<<M_ROWS / 256, 256, 0, stream>>>(candg_s, candg_i,
                                                          fixlist, fixcount, out);
  } else {
    // round-1 fallback (fits in ~35 MB; never taken on this harness)
    float* ws    = (float*)d_ws;
    float* proj1 = ws;
    float* invr1 = proj1 + (size_t)M_ROWS * E_DIM;
    float* invc1 = invr1 + M_ROWS;
    float* cnsq1 = invc1 + K_CB;
    float* cands = cnsq1 + K_CB;
    int*   candi1 = (int*)(cands + (size_t)M_ROWS * 2);

    row_norm_kernel<<<K_CB / 4, 256, 0, stream>>>(cb, invc1, cnsq1, nullptr);
    gemm1_kernel<<<dim3(E_DIM / 128, M_ROWS / 128), 256, 0, stream>>>(x, rp, proj1);
    row_norm_kernel<<<M_ROWS / 4, 256, 0, stream>>>(proj1, invr1, nullptr, nullptr);
    argmax_kernel<<<dim3(M_ROWS / 64, 2), 256, 0, stream>>>(proj1, cb, invr1,
                                                            invc1, cnsq1, cands, candi1);
    combine_kernel<<<M_ROWS / 256, 256, 0, stream>>>(cands, candi1, out);
  }
}

// Round 11
// 439.175 us; speedup vs baseline: 1.6780x; 1.0229x over previous
//
#include <hip/hip_runtime.h>
#include <hip/hip_bf16.h>

// Problem: RandomProjectionQuantizer  B=4 N=4096 D=1024 E=512 K=4096
// M = B*N = 16384 rows.
// proj = X @ P (fp32), scores = 2*invr_m*invc_k*(cb_k . proj_m) - cnsq_k,
// nearest = argmax_k score (ties -> min k).
// Round 11: LDS-FREE mfma_argmax K-loop.  Operands are pre-staged in exact
// fragment order, so each wave loads its 24 fragments per K-chunk straight
// to VGPRs (global_load_dwordx4) - no LDS staging, no __syncthreads, no
// vmcnt(0) barrier drain (the documented m97-structure plateau).  2x global
// traffic (L2-served) traded for barrier-free MFMA issue.  Grid swizzled
// 4mb x 8nb tiles for L2 locality.

#define M_ROWS 16384
#define D_DIM  1024
#define E_DIM  512
#define K_CB   4096
#define EPS_N  1e-12f
#define TAU_FIX 1e-4f
#define NEG_INF (-3.4e38f)

typedef short bf16x8 __attribute__((ext_vector_type(8)));
typedef _Float16 f16x8 __attribute__((ext_vector_type(8)));
typedef short s16x4 __attribute__((ext_vector_type(4)));
typedef float f32x4  __attribute__((ext_vector_type(4)));

// ---------------------------------------------------------------- helpers
__device__ __forceinline__ unsigned short f32_to_bf16_rtne(float x) {
  unsigned u = __float_as_uint(x);
  unsigned r = u + 0x7FFFu + ((u >> 16) & 1u);
  return (unsigned short)(r >> 16);
}
__device__ __forceinline__ float bf16_bits_to_f32(unsigned short h) {
  return __uint_as_float(((unsigned)h) << 16);
}
__device__ __forceinline__ void split_f16(float x, short& hs, short& ls) {
  _Float16 h = (_Float16)x;
  float hf = (float)h;
  _Float16 l = (_Float16)(x - hf);
  hs = __builtin_bit_cast(short, h);
  ls = __builtin_bit_cast(short, l);
}
__device__ __forceinline__ void g2l16(const void* g, void* l) {
  __builtin_amdgcn_global_load_lds(
      (const __attribute__((address_space(1))) unsigned*)g,
      (__attribute__((address_space(3))) unsigned*)l, 16, 0, 0);
}

// ---------------------------------------------------------------- row norms
__global__ __launch_bounds__(256) void row_norm_kernel(
    const float* __restrict__ src, float* __restrict__ inv_out,
    float* __restrict__ sq_out, int* __restrict__ zero_me) {
  if (zero_me && blockIdx.x == 0 && threadIdx.x == 0) *zero_me = 0;
  int row  = blockIdx.x * 4 + (threadIdx.x >> 6);
  int lane = threadIdx.x & 63;
  const float4* p = (const float4*)(src + (size_t)row * E_DIM);
  float4 v0 = p[lane];
  float4 v1 = p[lane + 64];
  float s = v0.x * v0.x + v0.y * v0.y + v0.z * v0.z + v0.w * v0.w +
            v1.x * v1.x + v1.y * v1.y + v1.z * v1.z + v1.w * v1.w;
#pragma unroll
  for (int m = 32; m; m >>= 1) s += __shfl_xor(s, m, 64);
  float d = fmaxf(sqrtf(s), EPS_N);
  if (sq_out) {
    float q0 = v0.x / d, q1 = v0.y / d, q2 = v0.z / d, q3 = v0.w / d;
    float q4 = v1.x / d, q5 = v1.y / d, q6 = v1.z / d, q7 = v1.w / d;
    float q = q0 * q0 + q1 * q1 + q2 * q2 + q3 * q3 +
              q4 * q4 + q5 * q5 + q6 * q6 + q7 * q7;
#pragma unroll
    for (int m = 32; m; m >>= 1) q += __shfl_xor(q, m, 64);
    if (lane == 0) sq_out[row] = q;
  }
  if (lane == 0) inv_out[row] = 1.0f / d;
}

// ---------------------------------------------------------------- cb norm+split
__global__ __launch_bounds__(256) void cbnorm_split_kernel(
    const float* __restrict__ cb, float* __restrict__ invc,
    float* __restrict__ cnsq, short* __restrict__ hi, short* __restrict__ lo,
    int* __restrict__ zero_me) {
  if (zero_me && blockIdx.x == 0 && threadIdx.x == 0) *zero_me = 0;
  int r    = blockIdx.x * 4 + (threadIdx.x >> 6);
  int lane = threadIdx.x & 63;
  const float* src = cb + (size_t)r * E_DIM + lane * 8;
  float4 v0 = *(const float4*)src;
  float4 v1 = *(const float4*)(src + 4);
  float v[8] = {v0.x, v0.y, v0.z, v0.w, v1.x, v1.y, v1.z, v1.w};
  float s = 0.f;
#pragma unroll
  for (int j = 0; j < 8; ++j) s = fmaf(v[j], v[j], s);
#pragma unroll
  for (int m = 32; m; m >>= 1) s += __shfl_xor(s, m, 64);
  float d = fmaxf(sqrtf(s), EPS_N);
  float q = 0.f;
#pragma unroll
  for (int j = 0; j < 8; ++j) { float t = v[j] / d; q = fmaf(t, t, q); }
#pragma unroll
  for (int m = 32; m; m >>= 1) q += __shfl_xor(q, m, 64);
  if (lane == 0) { cnsq[r] = q; invc[r] = 1.0f / d; }
  union { short s8[8]; float4 f; } H, L;
#pragma unroll
  for (int j = 0; j < 8; ++j) {
    unsigned short h = f32_to_bf16_rtne(v[j]);
    float hf = bf16_bits_to_f32(h);
    H.s8[j] = (short)h;
    L.s8[j] = (short)f32_to_bf16_rtne(v[j] - hf);
  }
  int rb = r >> 7, row = r & 127;
  int kc = lane >> 2, qq = lane & 3;
  size_t idx = (((size_t)(rb * 16 + kc) * 512) + qq * 128 + row) * 8;
  *(float4*)(hi + idx) = H.f;
  *(float4*)(lo + idx) = L.f;
}

// ---------------------------------------------------------------- P split
__global__ __launch_bounds__(256) void psplit_kernel(
    const float* __restrict__ P, short* __restrict__ Ph,
    short* __restrict__ Pl) {
  int tid = threadIdx.x;
#pragma unroll
  for (int i = 0; i < 4; ++i) {
    int g = blockIdx.x * 1024 + i * 256 + tid;  // 0..65535
    int k8 = g >> 9, col = g & 511;
    int nb = col >> 7, c = col & 127;
    int kc = k8 >> 2, q = k8 & 3;
    union { short s8[8]; float4 f; } H, L;
#pragma unroll
    for (int j = 0; j < 8; ++j) {
      float v = P[(size_t)(k8 * 8 + j) * 512 + col] * 4096.0f;
      split_f16(v, H.s8[j], L.s8[j]);
    }
    size_t dst = (((size_t)(nb * 32 + kc) * 4 + q) * 128 + c) * 8;
    *(float4*)(Ph + dst) = H.f;
    *(float4*)(Pl + dst) = L.f;
  }
}

// ---------------------------------------------------------------- GEMM1 (MFMA)
// proj = X @ P via fp16-split MFMA (hh+hl+lh), scale 4096^2 backed out.
__global__ __launch_bounds__(256, 2) void gemm1_mfma_kernel(
    const float* __restrict__ X, const short* __restrict__ Ph,
    const short* __restrict__ Pl, float* __restrict__ proj,
    short* __restrict__ Ah, short* __restrict__ Al) {
  __shared__ short lds_ah[4096];
  __shared__ short lds_al[4096];
  __shared__ short lds_bh[4096];
  __shared__ short lds_bl[4096];
  int tid = threadIdx.x;
  int wid = tid >> 6, lane = tid & 63;
  int nb = blockIdx.x, mb = blockIdx.y;
  int m0 = mb * 128, n0 = nb * 128;
  int wm = wid >> 1, wn = wid & 1;
  int q4 = lane >> 4, c0 = lane & 15;

  f32x4 zero = {0.f, 0.f, 0.f, 0.f};
  f32x4 acc[4][4];
#pragma unroll
  for (int i = 0; i < 4; ++i)
#pragma unroll
    for (int j = 0; j < 4; ++j) acc[i][j] = zero;

  for (int kc = 0; kc < 32; ++kc) {
    const char* gb = (const char*)Ph + ((size_t)(nb * 32 + kc)) * 8192;
    const char* gl = (const char*)Pl + ((size_t)(nb * 32 + kc)) * 8192;
#pragma unroll
    for (int p = 0; p < 4; ++p) {
      int s = wid * 4 + p;
      int t = s >> 3;
      int off = (s & 7) * 1024;
      const char* src = (t == 0 ? gb : gl) + off + lane * 16;
      char* dst = (char*)(t == 0 ? lds_bh : lds_bl) + off;
      g2l16(src, dst);
    }
#pragma unroll
    for (int i = 0; i < 4; ++i) {
      int e = i * 1024 + tid * 4;
      int row = e >> 5, k4 = e & 31;
      int q = k4 >> 3, j0 = k4 & 7;
      float4 xv = *(const float4*)(X + (size_t)(m0 + row) * D_DIM + kc * 32 + k4);
      float v[4] = {xv.x * 4096.f, xv.y * 4096.f, xv.z * 4096.f, xv.w * 4096.f};
      s16x4 H, L;
#pragma unroll
      for (int j = 0; j < 4; ++j) {
        short hs, ls;
        split_f16(v[j], hs, ls);
        H[j] = hs; L[j] = ls;
      }
      int o = (q * 128 + row) * 8 + j0;
      *(s16x4*)&lds_ah[o] = H;
      *(s16x4*)&lds_al[o] = L;
    }
    __syncthreads();

    f16x8 bh[4], bl[4];
#pragma unroll
    for (int ni = 0; ni < 4; ++ni) {
      int boff = (q4 * 128 + wn * 64 + ni * 16 + c0) * 8;
      bh[ni] = *(const f16x8*)&lds_bh[boff];
      bl[ni] = *(const f16x8*)&lds_bl[boff];
    }
#pragma unroll
    for (int mi = 0; mi < 4; ++mi) {
      int aoff = (q4 * 128 + wm * 64 + mi * 16 + c0) * 8;
      f16x8 ah = *(const f16x8*)&lds_ah[aoff];
      f16x8 al = *(const f16x8*)&lds_al[aoff];
#pragma unroll
      for (int ni = 0; ni < 4; ++ni) {
        acc[mi][ni] = __builtin_amdgcn_mfma_f32_16x16x32_f16(
            ah, bh[ni], acc[mi][ni], 0, 0, 0);
        acc[mi][ni] = __builtin_amdgcn_mfma_f32_16x16x32_f16(
            ah, bl[ni], acc[mi][ni], 0, 0, 0);
        acc[mi][ni] = __builtin_amdgcn_mfma_f32_16x16x32_f16(
            al, bh[ni], acc[mi][ni], 0, 0, 0);
      }
    }
    __syncthreads();
  }

  const float inv_s = 1.0f / 16777216.0f;
#pragma unroll
  for (int ni = 0; ni < 4; ++ni) {
    int gcol = n0 + wn * 64 + ni * 16 + c0;
    int kce = gcol >> 5, qe = (gcol & 31) >> 3, je = gcol & 7;
#pragma unroll
    for (int mi = 0; mi < 4; ++mi) {
#pragma unroll
      for (int r = 0; r < 4; ++r) {
        int rl = wm * 64 + mi * 16 + q4 * 4 + r;
        float val = acc[mi][ni][r] * inv_s;
        proj[(size_t)(m0 + rl) * E_DIM + gcol] = val;
        unsigned short hb = f32_to_bf16_rtne(val);
        size_t idx = (((size_t)(mb * 16 + kce) * 512) + qe * 128 + rl) * 8 + je;
        Ah[idx] = (short)hb;
        Al[idx] = (short)f32_to_bf16_rtne(val - bf16_bits_to_f32(hb));
      }
    }
  }
}

// ---------------------------------------------------------------- MFMA argmax
// LDS-FREE K-loop.  grid 2048 linear, swizzled into 4mb x 8nb tiles.
// Block tile 256x128, 4 waves 2x2 (wm picks the 128-row half = rb,
// wn picks the 64-col half).  Each wave loads its 24 fragments per K-chunk
// directly from the pre-staged arrays (global dwordx4) - no LDS, no
// __syncthreads, no barrier vmcnt(0) drain.  LDS used only for the epilogue
// cross-wave merge.
__global__ __launch_bounds__(256, 2) void mfma_argmax_kernel(
    const short* __restrict__ Ah, const short* __restrict__ Al,
    const short* __restrict__ Bh, const short* __restrict__ Bl,
    const float* __restrict__ invr, const float* __restrict__ invc,
    const float* __restrict__ cnsq, float* __restrict__ candb,
    float* __restrict__ cands2, int* __restrict__ candi) {
  __shared__ float msb[512];
  __shared__ float mss[512];
  __shared__ int   msi[512];
  int tid = threadIdx.x;
  int wid = tid >> 6, lane = tid & 63;
  // swizzle: 32-block tiles of 4 mb x 8 nb for per-XCD L2 locality
  int lin = blockIdx.x;
  int tile = lin >> 5, wi = lin & 31;
  int tnb = tile & 3, tmb = tile >> 2;
  int nb = tnb * 8 + (wi & 7);
  int mb = tmb * 4 + (wi >> 3);

  int wm = wid >> 1, wn = wid & 1;
  int q = lane >> 4, c0 = lane & 15;
  int rb = mb * 2 + wm;

  // per-lane fragment base pointers (element units = shorts)
  const short* pAh = Ah + (((size_t)rb * 16) * 512 + q * 128 + c0) * 8;
  const short* pAl = Al + (((size_t)rb * 16) * 512 + q * 128 + c0) * 8;
  const short* pBh = Bh + (((size_t)nb * 16) * 512 + q * 128 + wn * 64 + c0) * 8;
  const short* pBl = Bl + (((size_t)nb * 16) * 512 + q * 128 + wn * 64 + c0) * 8;

  f32x4 zero = {0.f, 0.f, 0.f, 0.f};
  f32x4 acc[8][4];
#pragma unroll
  for (int i = 0; i < 8; ++i)
#pragma unroll
    for (int j = 0; j < 4; ++j) acc[i][j] = zero;

  for (int kc = 0; kc < 16; ++kc) {
    size_t ko = (size_t)kc * 4096;  // 512*8 shorts per chunk
    bf16x8 bh[4], bl[4], ah[8], al[8];
#pragma unroll
    for (int ni = 0; ni < 4; ++ni) {
      bh[ni] = *(const bf16x8*)(pBh + ko + ni * 128);
      bl[ni] = *(const bf16x8*)(pBl + ko + ni * 128);
    }
#pragma unroll
    for (int mi = 0; mi < 8; ++mi) {
      ah[mi] = *(const bf16x8*)(pAh + ko + mi * 128);
      al[mi] = *(const bf16x8*)(pAl + ko + mi * 128);
    }
#pragma unroll
    for (int mi = 0; mi < 8; ++mi) {
#pragma unroll
      for (int ni = 0; ni < 4; ++ni) {
        acc[mi][ni] = __builtin_amdgcn_mfma_f32_16x16x32_bf16(
            ah[mi], bh[ni], acc[mi][ni], 0, 0, 0);
        acc[mi][ni] = __builtin_amdgcn_mfma_f32_16x16x32_bf16(
            ah[mi], bl[ni], acc[mi][ni], 0, 0, 0);
        acc[mi][ni] = __builtin_amdgcn_mfma_f32_16x16x32_bf16(
            al[mi], bh[ni], acc[mi][ni], 0, 0, 0);
      }
    }
  }

  // epilogue: per-wave top-2 over its 64 columns, LDS merge of wn halves.
  float icv[4], cqv[4];
#pragma unroll
  for (int ni = 0; ni < 4; ++ni) {
    int n = nb * 128 + wn * 64 + ni * 16 + c0;
    icv[ni] = invc[n];
    cqv[ni] = cnsq[n];
  }
#pragma unroll
  for (int mi = 0; mi < 8; ++mi) {
    float4 ir4 = *(const float4*)&invr[mb * 256 + wm * 128 + mi * 16 + q * 4];
    float irv[4] = {ir4.x, ir4.y, ir4.z, ir4.w};
#pragma unroll
    for (int r = 0; r < 4; ++r) {
      float tir = 2.0f * irv[r];
      float b = NEG_INF, s = NEG_INF;
      int bi = 2147483647;
#pragma unroll
      for (int ni = 0; ni < 4; ++ni) {
        float v = acc[mi][ni][r] * tir * icv[ni] - cqv[ni];
        int n = nb * 128 + wn * 64 + ni * 16 + c0;
        if (v > b) { s = b; b = v; bi = n; } else { s = fmaxf(s, v); }
      }
#pragma unroll
      for (int off = 1; off < 16; off <<= 1) {
        float ob = __shfl_xor(b, off, 64);
        float os = __shfl_xor(s, off, 64);
        int   oi = __shfl_xor(bi, off, 64);
        if (ob > b || (ob == b && oi < bi)) {
          s = fmaxf(b, os); b = ob; bi = oi;
        } else {
          s = fmaxf(s, ob);
        }
      }
      if (c0 == 0) {
        int rl = wm * 128 + mi * 16 + q * 4 + r;  // 0..255 within block
        msb[wn * 256 + rl] = b;
        mss[wn * 256 + rl] = s;
        msi[wn * 256 + rl] = bi;
      }
    }
  }
  __syncthreads();
  {
    float b0 = msb[tid],       s0 = mss[tid];
    float b1 = msb[256 + tid], s1 = mss[256 + tid];
    int   i0 = msi[tid],       i1 = msi[256 + tid];
    float B, S; int I;
    if (b1 > b0 || (b1 == b0 && i1 < i0)) {
      B = b1; S = fmaxf(s1, b0); I = i1;
    } else {
      B = b0; S = fmaxf(s0, b1); I = i0;
    }
    size_t o = (size_t)(mb * 256 + tid) * 32 + nb;
    candb[o] = B; cands2[o] = S; candi[o] = I;
  }
}

// ---------------------------------------------------------------- combine
__global__ __launch_bounds__(256) void combine2_kernel(
    const float* __restrict__ candb, const float* __restrict__ cands2,
    const int* __restrict__ candi, int* __restrict__ out,
    int* __restrict__ fixlist, int* __restrict__ fixcount) {
  int r = blockIdx.x * 256 + threadIdx.x;
  float b = NEG_INF, s = NEG_INF;
  int bi = 2147483647;
  const float* pb = candb + (size_t)r * 32;
  const float* ps = cands2 + (size_t)r * 32;
  const int*   pi = candi + (size_t)r * 32;
#pragma unroll 4
  for (int j = 0; j < 32; ++j) {
    float cb_ = pb[j], cs_ = ps[j];
    int ci_ = pi[j];
    if (cb_ > b || (cb_ == b && ci_ < bi)) {
      s = fmaxf(b, cs_); b = cb_; bi = ci_;
    } else {
      s = fmaxf(s, cb_);
    }
  }
  out[r] = bi;
  if (b - s < TAU_FIX) {
    int p = atomicAdd(fixcount, 1);
    if (p < M_ROWS) fixlist[p] = r;
  }
}

// ---------------------------------------------------------------- fixup
__global__ __launch_bounds__(256) void fix_argmax2_kernel(
    const float* __restrict__ P, const float* __restrict__ CB,
    const float* __restrict__ invr, const float* __restrict__ invc,
    const float* __restrict__ cnsq, const int* __restrict__ fixlist,
    const int* __restrict__ fixcount, float* __restrict__ cand_s,
    int* __restrict__ cand_i) {
  int n = *fixcount;
  if (n > M_ROWS) n = M_ROWS;
  int ngroups = (n + 3) >> 2;
  if ((int)blockIdx.y >= ngroups) return;
  __shared__ float wb[4][4];
  __shared__ int   wi[4][4];
  int tid = threadIdx.x, wv = tid >> 6, lane = tid & 63;
  int kbase = blockIdx.x * 256 + wv * 64;

  for (int g = blockIdx.y; g < ngroups; g += 64) {
    int it0 = g * 4;
    int rcount = n - it0; if (rcount > 4) rcount = 4;
    float4 p0[4], p1[4];
    float tir[4];
#pragma unroll
    for (int j = 0; j < 4; ++j) {
      int it = it0 + (j < rcount ? j : 0);
      int r = fixlist[it];
      const float* pr = P + (size_t)r * E_DIM + lane * 8;
      p0[j] = *(const float4*)pr;
      p1[j] = *(const float4*)(pr + 4);
      tir[j] = 2.0f * invr[r];
    }
    float best[4];
    int   bidx[4];
#pragma unroll
    for (int j = 0; j < 4; ++j) { best[j] = NEG_INF; bidx[j] = 2147483647; }
#pragma unroll 2
    for (int i = 0; i < 64; ++i) {
      int k = kbase + i;
      const float* cr = CB + (size_t)k * E_DIM + lane * 8;
      float4 c0 = *(const float4*)cr;
      float4 c1 = *(const float4*)(cr + 4);
      float d[4];
#pragma unroll
      for (int j = 0; j < 4; ++j) {
        float t = 0.f;
        t = fmaf(c0.x, p0[j].x, t); t = fmaf(c0.y, p0[j].y, t);
        t = fmaf(c0.z, p0[j].z, t); t = fmaf(c0.w, p0[j].w, t);
        t = fmaf(c1.x, p1[j].x, t); t = fmaf(c1.y, p1[j].y, t);
        t = fmaf(c1.z, p1[j].z, t); t = fmaf(c1.w, p1[j].w, t);
        d[j] = t;
      }
#pragma unroll
      for (int m = 1; m < 64; m <<= 1) {
#pragma unroll
        for (int j = 0; j < 4; ++j) d[j] += __shfl_xor(d[j], m, 64);
      }
      float ic = invc[k], cq = cnsq[k];
#pragma unroll
      for (int j = 0; j < 4; ++j) {
        float sc = tir[j] * ic * d[j] - cq;
        if (sc > best[j]) { best[j] = sc; bidx[j] = k; }
      }
    }
    if (lane == 0) {
#pragma unroll
      for (int j = 0; j < 4; ++j) { wb[wv][j] = best[j]; wi[wv][j] = bidx[j]; }
    }
    __syncthreads();
    if (tid < 4 && tid < rcount) {
      int j = tid;
      float b = wb[0][j];
      int bi = wi[0][j];
#pragma unroll
      for (int w2 = 1; w2 < 4; ++w2) {
        if (wb[w2][j] > b || (wb[w2][j] == b && wi[w2][j] < bi)) {
          b = wb[w2][j]; bi = wi[w2][j];
        }
      }
      size_t o = (size_t)(it0 + j) * 16 + blockIdx.x;
      cand_s[o] = b; cand_i[o] = bi;
    }
    __syncthreads();
  }
}

__global__ __launch_bounds__(256) void fix_combine2_kernel(
    const float* __restrict__ cand_s, const int* __restrict__ cand_i,
    const int* __restrict__ fixlist, const int* __restrict__ fixcount,
    int* __restrict__ out) {
  int n = *fixcount;
  if (n > M_ROWS) n = M_ROWS;
  int it = blockIdx.x * 256 + threadIdx.x;
  if (it >= n) return;
  float b = NEG_INF;
  int bi = 2147483647;
#pragma unroll 4
  for (int c = 0; c < 16; ++c) {
    float s = cand_s[(size_t)it * 16 + c];
    int ii = cand_i[(size_t)it * 16 + c];
    if (s > b || (s == b && ii < bi)) { b = s; bi = ii; }
  }
  out[fixlist[it]] = bi;
}

// ================================================================ fallback
__global__ __launch_bounds__(256, 2) void gemm1_kernel(
    const float* __restrict__ A, const float* __restrict__ Bm,
    float* __restrict__ C) {
  __shared__ float As[2][16][132];
  __shared__ float Bs[2][16][128];
  int tid = threadIdx.x;
  int tx = tid & 15, ty = tid >> 4;
  int n0 = blockIdx.x * 128;
  int m0 = blockIdx.y * 128;

  int arow = tid >> 2;
  int akq  = (tid & 3) * 4;
  int bk   = tid >> 5;
  int bcol = (tid & 31) * 4;

  const float* Aptr  = A + (size_t)(m0 + arow) * D_DIM + akq;
  const float* Aptr2 = Aptr + (size_t)64 * D_DIM;
  const float* Bptr  = Bm + (size_t)bk * E_DIM + n0 + bcol;
  const float* Bptr2 = Bptr + (size_t)8 * E_DIM;

  float acc[8][8] = {};
  float4 a0 = *(const float4*)(Aptr);
  float4 a1 = *(const float4*)(Aptr2);
  float4 b0 = *(const float4*)(Bptr);
  float4 b1 = *(const float4*)(Bptr2);

  int buf = 0;
  for (int k0 = 0; k0 < D_DIM; k0 += 16) {
    As[buf][akq + 0][arow] = a0.x;
    As[buf][akq + 1][arow] = a0.y;
    As[buf][akq + 2][arow] = a0.z;
    As[buf][akq + 3][arow] = a0.w;
    As[buf][akq + 0][arow + 64] = a1.x;
    As[buf][akq + 1][arow + 64] = a1.y;
    As[buf][akq + 2][arow + 64] = a1.z;
    As[buf][akq + 3][arow + 64] = a1.w;
    *(float4*)&Bs[buf][bk][bcol]     = b0;
    *(float4*)&Bs[buf][bk + 8][bcol] = b1;
    __syncthreads();
    if (k0 + 16 < D_DIM) {
      a0 = *(const float4*)(Aptr + k0 + 16);
      a1 = *(const float4*)(Aptr2 + k0 + 16);
      b0 = *(const float4*)(Bptr + (size_t)(k0 + 16) * E_DIM);
      b1 = *(const float4*)(Bptr2 + (size_t)(k0 + 16) * E_DIM);
    }
#pragma unroll
    for (int kk = 0; kk < 16; ++kk) {
      float4 av0 = *(const float4*)&As[buf][kk][ty * 8];
      float4 av1 = *(const float4*)&As[buf][kk][ty * 8 + 4];
      float4 bv0 = *(const float4*)&Bs[buf][kk][tx * 4];
      float4 bv1 = *(const float4*)&Bs[buf][kk][tx * 4 + 64];
      float a[8] = {av0.x, av0.y, av0.z, av0.w, av1.x, av1.y, av1.z, av1.w};
      float b[8] = {bv0.x, bv0.y, bv0.z, bv0.w, bv1.x, bv1.y, bv1.z, bv1.w};
#pragma unroll
      for (int i = 0; i < 8; ++i)
#pragma unroll
        for (int j = 0; j < 8; ++j) acc[i][j] = fmaf(a[i], b[j], acc[i][j]);
    }
    buf ^= 1;
  }
#pragma unroll
  for (int i = 0; i < 8; ++i) {
    float* crow = C + (size_t)(m0 + ty * 8 + i) * E_DIM + n0;
    *(float4*)(crow + tx * 4)      = make_float4(acc[i][0], acc[i][1], acc[i][2], acc[i][3]);
    *(float4*)(crow + tx * 4 + 64) = make_float4(acc[i][4], acc[i][5], acc[i][6], acc[i][7]);
  }
}

__global__ __launch_bounds__(256, 2) void argmax_kernel(
    const float* __restrict__ P, const float* __restrict__ CB,
    const float* __restrict__ invr, const float* __restrict__ invc,
    const float* __restrict__ cnsq, float* __restrict__ cand_s,
    int* __restrict__ cand_i) {
  __shared__ float As[2][16][68];
  __shared__ float Bs[2][16][256];
  __shared__ float invr_s[64];
  __shared__ float red_s[64][33];
  __shared__ int   red_i[64][33];

  int tid = threadIdx.x;
  int tx = tid & 31, ty = tid >> 5;
  int m0 = blockIdx.x * 64;
  int cbase = blockIdx.y * 2048;
  if (tid < 64) invr_s[tid] = invr[m0 + tid];
  int arow = tid >> 2;
  int akq  = (tid & 3) * 4;
  const float* Aptr = P + (size_t)(m0 + arow) * E_DIM + akq;

  float best[8];
  int   bidx[8];
#pragma unroll
  for (int i = 0; i < 8; ++i) { best[i] = NEG_INF; bidx[i] = 0; }

  for (int n0 = 0; n0 < 2048; n0 += 256) {
    const float* Bptr = CB + (size_t)(cbase + n0 + tid) * E_DIM;
    float4 a0 = *(const float4*)(Aptr);
    float4 b0 = *(const float4*)(Bptr + 0);
    float4 b1 = *(const float4*)(Bptr + 4);
    float4 b2 = *(const float4*)(Bptr + 8);
    float4 b3 = *(const float4*)(Bptr + 12);
    float acc[8][8] = {};
    int buf = 0;
    for (int k0 = 0; k0 < E_DIM; k0 += 16) {
      As[buf][akq + 0][arow] = a0.x;
      As[buf][akq + 1][arow] = a0.y;
      As[buf][akq + 2][arow] = a0.z;
      As[buf][akq + 3][arow] = a0.w;
      Bs[buf][0][tid] = b0.x;  Bs[buf][1][tid] = b0.y;
      Bs[buf][2][tid] = b0.z;  Bs[buf][3][tid] = b0.w;
      Bs[buf][4][tid] = b1.x;  Bs[buf][5][tid] = b1.y;
      Bs[buf][6][tid] = b1.z;  Bs[buf][7][tid] = b1.w;
      Bs[buf][8][tid] = b2.x;  Bs[buf][9][tid] = b2.y;
      Bs[buf][10][tid] = b2.z; Bs[buf][11][tid] = b2.w;
      Bs[buf][12][tid] = b3.x; Bs[buf][13][tid] = b3.y;
      Bs[buf][14][tid] = b3.z; Bs[buf][15][tid] = b3.w;
      __syncthreads();
      if (k0 + 16 < E_DIM) {
        a0 = *(const float4*)(Aptr + k0 + 16);
        b0 = *(const float4*)(Bptr + k0 + 16);
        b1 = *(const float4*)(Bptr + k0 + 20);
        b2 = *(const float4*)(Bptr + k0 + 24);
        b3 = *(const float4*)(Bptr + k0 + 28);
      }
#pragma unroll
      for (int kk = 0; kk < 16; ++kk) {
        float4 av0 = *(const float4*)&As[buf][kk][ty * 8];
        float4 av1 = *(const float4*)&As[buf][kk][ty * 8 + 4];
        float4 bv0 = *(const float4*)&Bs[buf][kk][tx * 4];
        float4 bv1 = *(const float4*)&Bs[buf][kk][tx * 4 + 128];
        float a[8] = {av0.x, av0.y, av0.z, av0.w, av1.x, av1.y, av1.z, av1.w};
        float b[8] = {bv0.x, bv0.y, bv0.z, bv0.w, bv1.x, bv1.y, bv1.z, bv1.w};
#pragma unroll
        for (int i = 0; i < 8; ++i)
#pragma unroll
          for (int j = 0; j < 8; ++j) acc[i][j] = fmaf(a[i], b[j], acc[i][j]);
      }
      buf ^= 1;
    }
#pragma unroll
    for (int j4 = 0; j4 < 2; ++j4) {
      int nbq = cbase + n0 + j4 * 128 + tx * 4;
      float4 ic = *(const float4*)&invc[nbq];
      float4 cq = *(const float4*)&cnsq[nbq];
      float icv[4] = {ic.x, ic.y, ic.z, ic.w};
      float cqv[4] = {cq.x, cq.y, cq.z, cq.w};
#pragma unroll
      for (int i = 0; i < 8; ++i) {
        float ir2 = 2.0f * invr_s[ty * 8 + i];
#pragma unroll
        for (int jj = 0; jj < 4; ++jj) {
          float sc = acc[i][j4 * 4 + jj] * ir2 * icv[jj] - cqv[jj];
          if (sc > best[i]) { best[i] = sc; bidx[i] = nbq + jj; }
        }
      }
    }
  }
  __syncthreads();
#pragma unroll
  for (int i = 0; i < 8; ++i) {
    red_s[ty * 8 + i][tx] = best[i];
    red_i[ty * 8 + i][tx] = bidx[i];
  }
  __syncthreads();
  if (tid < 64) {
    float bs = red_s[tid][0];
    int bi = red_i[tid][0];
#pragma unroll
    for (int t = 1; t < 32; ++t) {
      float s = red_s[tid][t];
      int ii = red_i[tid][t];
      if (s > bs || (s == bs && ii < bi)) { bs = s; bi = ii; }
    }
    cand_s[(size_t)(m0 + tid) * 2 + blockIdx.y] = bs;
    cand_i[(size_t)(m0 + tid) * 2 + blockIdx.y] = bi;
  }
}

__global__ __launch_bounds__(256) void combine_kernel(
    const float* __restrict__ cand_s, const int* __restrict__ cand_i,
    int* __restrict__ out) {
  int r = blockIdx.x * 256 + threadIdx.x;
  float s0 = cand_s[r * 2], s1 = cand_s[r * 2 + 1];
  int i0 = cand_i[r * 2], i1 = cand_i[r * 2 + 1];
  out[r] = (s1 > s0 || (s1 == s0 && i1 < i0)) ? i1 : i0;
}

// ---------------------------------------------------------------- launch
extern "C" void kernel_launch(void* const* d_in, const int* in_sizes, int n_in,
                              void* d_out, int out_size, void* d_ws, size_t ws_size,
                              hipStream_t stream) {
  const float* x  = (const float*)d_in[0];
  const float* rp = (const float*)d_in[1];
  const float* cb = (const float*)d_in[2];
  int* out = (int*)d_out;

  char* w = (char*)d_ws;
  float* proj = (float*)w;      w += (size_t)M_ROWS * E_DIM * 4;   // 32 MB
  short* Ah   = (short*)w;      w += (size_t)M_ROWS * E_DIM * 2;   // 16 MB
  short* Al   = (short*)w;      w += (size_t)M_ROWS * E_DIM * 2;   // 16 MB
  short* Bh   = (short*)w;      w += (size_t)K_CB * E_DIM * 2;     // 4 MB
  short* Bl   = (short*)w;      w += (size_t)K_CB * E_DIM * 2;     // 4 MB
  float* invr = (float*)w;      w += M_ROWS * 4;
  float* invc = (float*)w;      w += K_CB * 4;
  float* cnsq = (float*)w;      w += K_CB * 4;
  float* candb  = (float*)w;    w += (size_t)M_ROWS * 32 * 4;      // 2 MB
  float* cands2 = (float*)w;    w += (size_t)M_ROWS * 32 * 4;      // 2 MB
  int*   candi  = (int*)w;      w += (size_t)M_ROWS * 32 * 4;      // 2 MB
  int*   fixlist  = (int*)w;    w += M_ROWS * 4;
  int*   fixcount = (int*)w;    w += 64;
  size_t need = (size_t)(w - (char*)d_ws);
  short* Ph = (short*)candb;    // overlay: dead until mfma_argmax writes
  short* Pl = (short*)cands2;
  float* candg_s = (float*)Ah;  // overlay: Ah dead after mfma_argmax
  int*   candg_i = (int*)((char*)Ah + (size_t)M_ROWS * 16 * 4);

  if (ws_size >= need) {
    cbnorm_split_kernel<<<K_CB / 4, 256, 0, stream>>>(cb, invc, cnsq, Bh, Bl,
                                                      fixcount);
    psplit_kernel<<<64, 256, 0, stream>>>(rp, Ph, Pl);
    gemm1_mfma_kernel<<<dim3(E_DIM / 128, M_ROWS / 128), 256, 0, stream>>>(
        x, Ph, Pl, proj, Ah, Al);
    row_norm_kernel<<<M_ROWS / 4, 256, 0, stream>>>(proj, invr, nullptr, nullptr);
    mfma_argmax_kernel<<<(M_ROWS / 256) * (K_CB / 128), 256, 0, stream>>>(
        Ah, Al, Bh, Bl, invr, invc, cnsq, candb, cands2, candi);
    combine2_kernel<<<M_ROWS / 256, 256, 0, stream>>>(candb, cands2, candi, out,
                                                      fixlist, fixcount);
    fix_argmax2_kernel<<<dim3(16, 64), 256, 0, stream>>>(
        proj, cb, invr, invc, cnsq, fixlist, fixcount, candg_s, candg_i);
    fix_combine2_kernel<<<M_ROWS / 256, 256, 0, stream>>>(candg_s, candg_i,
                                                          fixlist, fixcount, out);
  } else {
    float* ws    = (float*)d_ws;
    float* proj1 = ws;
    float* invr1 = proj1 + (size_t)M_ROWS * E_DIM;
    float* invc1 = invr1 + M_ROWS;
    float* cnsq1 = invc1 + K_CB;
    float* cands = cnsq1 + K_CB;
    int*   candi1 = (int*)(cands + (size_t)M_ROWS * 2);

    row_norm_kernel<<<K_CB / 4, 256, 0, stream>>>(cb, invc1, cnsq1, nullptr);
    gemm1_kernel<<<dim3(E_DIM / 128, M_ROWS / 128), 256, 0, stream>>>(x, rp, proj1);
    row_norm_kernel<<<M_ROWS / 4, 256, 0, stream>>>(proj1, invr1, nullptr, nullptr);
    argmax_kernel<<<dim3(M_ROWS / 64, 2), 256, 0, stream>>>(proj1, cb, invr1,
                                                            invc1, cnsq1, cands, candi1);
    combine_kernel<<<M_ROWS / 256, 256, 0, stream>>>(cands, candi1, out);
  }
}